// Round 14
// baseline (434.656 us; speedup 1.0000x reference)
//
#include <hip/hip_runtime.h>
#include <hip/hip_bf16.h>
#include <stdint.h>

typedef __bf16 bf16x8 __attribute__((ext_vector_type(8)));
typedef float f32x4 __attribute__((ext_vector_type(4)));
typedef float f32x16 __attribute__((ext_vector_type(16)));
typedef float f32x4v __attribute__((ext_vector_type(4)));
typedef unsigned short u16;
typedef unsigned int u32;
typedef u16 u16x8 __attribute__((ext_vector_type(8)));
typedef u32 u32x4 __attribute__((ext_vector_type(4)));

#define B_ 2
#define S_ 2048
#define HID_ 2048
#define H_ 16
#define HK_ 4
#define D_ 128
#define NQKV_ 3072

__device__ __forceinline__ u16 f2bf(float f) {
  u32 u = __builtin_bit_cast(u32, f);
  u32 r = (u + 0x7fffu + ((u >> 16) & 1u)) >> 16;
  return (u16)r;
}
__device__ __forceinline__ float bf2f(u16 v) {
  u32 u = ((u32)v) << 16;
  return __builtin_bit_cast(float, u);
}
__device__ __forceinline__ u32 cvtpk(float lo, float hi) {
  u32 r;
  asm("v_cvt_pk_bf16_f32 %0, %1, %2" : "=v"(r) : "v"(lo), "v"(hi));
  return r;
}
__device__ __forceinline__ void gload_lds16(const void* g, void* l) {
  __builtin_amdgcn_global_load_lds((const __attribute__((address_space(1))) void*)g,
                                   (__attribute__((address_space(3))) void*)l, 16, 0, 0);
}

// ---------------- fused f32 -> bf16 convert for 3 buffers ----------------
__global__ __launch_bounds__(256) void k_cvt3(const float* __restrict__ a, u16* __restrict__ oa, int na,
                                              const float* __restrict__ b, u16* __restrict__ ob, int nb,
                                              const float* __restrict__ c, u16* __restrict__ oc, int nc) {
  int total = na + nb + nc;
  for (int i = blockIdx.x * 256 + threadIdx.x; i < total; i += gridDim.x * 256) {
    const float* src;
    u16* dst;
    int j = i;
    if (j < na) { src = a; dst = oa; }
    else if (j < na + nb) { j -= na; src = b; dst = ob; }
    else { j -= na + nb; src = c; dst = oc; }
    const f32x4v* p = (const f32x4v*)(src + (size_t)j * 8);
    f32x4v x = p[0], y = p[1];
    u16x8 w;
    w[0] = f2bf(x[0]); w[1] = f2bf(x[1]); w[2] = f2bf(x[2]); w[3] = f2bf(x[3]);
    w[4] = f2bf(y[0]); w[5] = f2bf(y[1]); w[6] = f2bf(y[2]); w[7] = f2bf(y[3]);
    *(u16x8*)(dst + (size_t)j * 8) = w;
  }
}

// ---------------- 8-phase deep-pipelined GEMM: C = A[M][K] . B[N][K]^T + bias ----
// T1: XCD-aware bijective block swizzle (nwg % 8 == 0 for all launches here).
template <int ISSUES>
__device__ __forceinline__ void stage_half(const u16* __restrict__ src, int K, char* ldsb, int tid) {
#pragma unroll
  for (int i = 0; i < ISSUES; ++i) {
    int off = i * 8192 + tid * 16;
    int r = off >> 7, cb = off & 127;
    int scb = cb ^ ((r & 7) << 4);
    gload_lds16((const char*)(src + (size_t)r * K) + scb, ldsb + i * 8192 + (tid & ~63) * 16);
  }
}

template <int BM, typename CT>
__global__ __launch_bounds__(512, 1) void k_gemm8p(const u16* __restrict__ A, const u16* __restrict__ Bm,
                                                   const float* __restrict__ bias, CT* __restrict__ C,
                                                   int M, int N, int K) {
  constexpr int HAR = BM / 2;            // rows per A half-tile
  constexpr int AHB = HAR * 128;         // bytes per A half-tile
  constexpr int AISS = AHB / 8192;       // gload issues per A half
  constexpr int MREP = BM / 32;          // 16-row frags per wave
  constexpr int MQ = MREP / 4;           // m-frags per phase
  constexpr int DB = 2 * AHB + 32768;    // dbuf stride
  __shared__ __attribute__((aligned(16))) char lds[2 * DB];
  const int tid = threadIdx.x, lane = tid & 63;
  const int wid = tid >> 6, wm = wid >> 2, wn = wid & 3;
  const int l15 = lane & 15, l4 = lane >> 4;
  // T1 swizzle: each XCD gets a contiguous chunk of tile space
  const int nwg = gridDim.x * gridDim.y;
  const int bid = blockIdx.y * gridDim.x + blockIdx.x;
  const int wgid = (bid & 7) * (nwg >> 3) + (bid >> 3);
  const int bx = wgid % gridDim.x, by = wgid / gridDim.x;
  const int row0 = by * BM, col0 = bx * 256;
  const int NT = K >> 6;

  f32x4 acc[MREP][4] = {};

  auto stageA = [&](int t, int h) {
    stage_half<AISS>(A + (size_t)(row0 + h * HAR) * K + t * 64, K, lds + (t & 1) * DB + h * AHB, tid);
  };
  auto stageB = [&](int t, int h) {
    stage_half<2>(Bm + (size_t)(col0 + h * 128) * K + t * 64, K, lds + (t & 1) * DB + 2 * AHB + h * 16384, tid);
  };

  stageA(0, 0); stageA(0, 1); stageB(0, 0); stageB(0, 1);
  if (NT > 1) { stageB(1, 0); stageB(1, 1); }
  if (NT > 1) asm volatile("s_waitcnt vmcnt(4)" ::: "memory");
  else        asm volatile("s_waitcnt vmcnt(0)" ::: "memory");
  __builtin_amdgcn_s_barrier();

  const char* myA = lds + wm * AHB;
  const char* myB = lds + 2 * AHB + (wn >> 1) * 16384;
  const int rBb = (wn & 1) * 64;

  for (int t = 0; t < NT; ++t) {
    const int d = t & 1;
    const char* Ab = myA + d * DB;
    const char* Bb = myB + d * DB;
    bf16x8 bfr[4][2];
#pragma unroll
    for (int j = 0; j < 4; ++j) {
      if (j == 0) {
#pragma unroll
        for (int n = 0; n < 4; ++n)
#pragma unroll
          for (int ks = 0; ks < 2; ++ks) {
            int r = rBb + n * 16 + l15;
            bfr[n][ks] = *(const bf16x8*)(Bb + r * 128 + ((ks * 64 + l4 * 16) ^ ((r & 7) << 4)));
          }
      }
      bf16x8 afr[MQ][2];
#pragma unroll
      for (int mq = 0; mq < MQ; ++mq)
#pragma unroll
        for (int ks = 0; ks < 2; ++ks) {
          int r = (j * MQ + mq) * 16 + l15;
          afr[mq][ks] = *(const bf16x8*)(Ab + r * 128 + ((ks * 64 + l4 * 16) ^ ((r & 7) << 4)));
        }
      if (j == 0) { if (t + 1 < NT) stageA(t + 1, 0); }
      else if (j == 1) { if (t + 1 < NT) stageA(t + 1, 1); }
      else if (j == 2) { if (t + 2 < NT) stageB(t + 2, 0); }
      else {
        if (t + 2 < NT) { stageB(t + 2, 1); asm volatile("s_waitcnt vmcnt(4)" ::: "memory"); }
        else             asm volatile("s_waitcnt vmcnt(0)" ::: "memory");
      }
      __builtin_amdgcn_s_barrier();
      asm volatile("s_waitcnt lgkmcnt(0)" ::: "memory");
      __builtin_amdgcn_s_setprio(1);
#pragma unroll
      for (int mq = 0; mq < MQ; ++mq)
#pragma unroll
        for (int ks = 0; ks < 2; ++ks)
#pragma unroll
          for (int n = 0; n < 4; ++n)
            acc[j * MQ + mq][n] =
                __builtin_amdgcn_mfma_f32_16x16x32_bf16(afr[mq][ks], bfr[n][ks], acc[j * MQ + mq][n], 0, 0, 0);
      __builtin_amdgcn_s_setprio(0);
      __builtin_amdgcn_s_barrier();
    }
  }

#pragma unroll
  for (int m = 0; m < MREP; ++m) {
    int grow = row0 + wm * HAR + m * 16 + l4 * 4;
#pragma unroll
    for (int n = 0; n < 4; ++n) {
      int gcol = col0 + wn * 64 + n * 16 + l15;
      float bv = bias[gcol];
#pragma unroll
      for (int r2 = 0; r2 < 4; ++r2) {
        float v = acc[m][n][r2] + bv;
        if constexpr (sizeof(CT) == 2) C[(size_t)(grow + r2) * N + gcol] = (CT)f2bf(v);
        else                           C[(size_t)(grow + r2) * N + gcol] = v;
      }
    }
  }
}

// ---------------- RoPE + split + layout (qkv bf16), vectorized bf16x8 ----------------
__global__ __launch_bounds__(256) void k_rope_split(const u16* __restrict__ qkv,
                                                    const float* __restrict__ cosb,
                                                    const float* __restrict__ sinb,
                                                    u16* __restrict__ Qb, u16* __restrict__ Kb,
                                                    u16* __restrict__ Vt) {
  const int bs = blockIdx.x;
  const int b = bs >> 11, s = bs & 2047;
  const size_t base = (size_t)bs * NQKV_;
  const size_t cs = (size_t)bs * D_;
  const int tid = threadIdx.x;
  const float qscale = 0.08838834764831845f;  // 1/sqrt(128)

  if (tid < 160) {
    const bool isq = tid < 128;
    const int idx = isq ? tid : (tid - 128);
    const int hh = idx >> 3, d0 = (idx & 7) * 8;
    const size_t srcb = base + (isq ? 0 : H_ * D_) + hh * D_;
    bf16x8 x1 = *(const bf16x8*)(qkv + srcb + d0);
    bf16x8 x2 = *(const bf16x8*)(qkv + srcb + d0 + 64);
    u16x8 y1, y2;
    const u16x8 u1 = __builtin_bit_cast(u16x8, x1);
    const u16x8 u2 = __builtin_bit_cast(u16x8, x2);
    const float sc = isq ? qscale : 1.0f;
#pragma unroll
    for (int i = 0; i < 8; ++i) {
      float f1 = bf2f(u1[i]), f2 = bf2f(u2[i]);
      float c1 = cosb[cs + d0 + i], s1 = sinb[cs + d0 + i];
      float c2 = cosb[cs + 64 + d0 + i], s2 = sinb[cs + 64 + d0 + i];
      y1[i] = f2bf((f1 * c1 - f2 * s1) * sc);
      y2[i] = f2bf((f2 * c2 + f1 * s2) * sc);
    }
    size_t o;
    if (isq) o = ((size_t)(b * H_ + hh) * S_ + s) * D_ + d0;
    else     o = ((size_t)(b * HK_ + hh) * S_ + s) * D_ + d0;
    u16* dst = isq ? Qb : Kb;
    *(u16x8*)(dst + o) = y1;
    *(u16x8*)(dst + o + 64) = y2;
  } else if (tid < 224) {
    const int idx = tid - 160;
    const int hk = idx >> 4, d0 = (idx & 15) * 8;
    bf16x8 xv = *(const bf16x8*)(qkv + base + (H_ + HK_) * D_ + hk * D_ + d0);
    const u16x8 uv = __builtin_bit_cast(u16x8, xv);
    u16* vb = Vt + (size_t)(b * HK_ + hk) * D_ * S_ + s;
#pragma unroll
    for (int i = 0; i < 8; ++i) vb[(size_t)(d0 + i) * S_] = uv[i];
  }
}

// ---------------- flash attention: 1024-thread WG = 2 KV-groups x 8 waves.
//  Each group = R7's proven pipeline (256 q-rows, dbuf, 1 barrier/kt) over its own
//  16 kv-tiles in a private 64KB LDS region (total 128KB). 16 waves/CU = 4/SIMD
//  by construction (single WG). Exact flash-merge of partials at the end. ----------------
__global__ __launch_bounds__(1024, 4) void k_attn(const u16* __restrict__ Qb, const u16* __restrict__ Kb,
                                                  const u16* __restrict__ Vt, u16* __restrict__ Ob) {
  __shared__ __attribute__((aligned(16))) char lds[131072];
  const int qt = blockIdx.x;  // 0..7
  const int bh = blockIdx.y;  // 0..31
  const int b = bh >> 4, h = bh & 15, hk = h >> 2;
  const int tid = threadIdx.x, lane = tid & 63, wid = tid >> 6;
  const int l31 = lane & 31, hi = lane >> 5;
  const int g = wid >> 3, wq = wid & 7;
  const int tid_g = tid & 511;

  const int qrow = qt * 256 + wq * 32 + l31;
  const u16* qptr = Qb + ((size_t)(b * H_ + h) * S_ + qrow) * D_;
  bf16x8 qf[8];
#pragma unroll
  for (int ks = 0; ks < 8; ++ks) qf[ks] = *(const bf16x8*)(qptr + ks * 16 + hi * 8);

  const u16* kbase = Kb + (size_t)(b * HK_ + hk) * S_ * D_;
  const u16* vbase = Vt + (size_t)(b * HK_ + hk) * D_ * S_;
  char* gregion = lds + g * 65536;  // group-private: buf d at +d*32768 (K 16K, V^T at +16384)

  int krow[2], kc[2], vrow[2], vc[2];
#pragma unroll
  for (int i = 0; i < 2; ++i) {
    int s = tid_g + i * 512;
    krow[i] = s >> 4; kc[i] = s & 15;
    vrow[i] = s >> 3; vc[i] = s & 7;
  }

  f32x16 o[4] = {};
  float mrun = -1e30f, lrun = 0.f;

  bf16x8 kreg[2], vreg[2];
  auto load_tile = [&](int T) {
#pragma unroll
    for (int i = 0; i < 2; ++i) {
      kreg[i] = *(const bf16x8*)(kbase + (size_t)(T * 64 + krow[i]) * D_ + kc[i] * 8);
      vreg[i] = *(const bf16x8*)(vbase + (size_t)vrow[i] * S_ + T * 64 + vc[i] * 8);
    }
  };
  auto write_tile = [&](int d) {
    char* nK = gregion + d * 32768;
    char* nV = nK + 16384;
#pragma unroll
    for (int i = 0; i < 2; ++i) {
      *(bf16x8*)(nK + ((krow[i] * 256 + kc[i] * 16) ^ ((krow[i] & 15) << 4))) = kreg[i];
      *(bf16x8*)(nV + ((vrow[i] * 128 + vc[i] * 16) ^ ((vrow[i] & 7) << 4))) = vreg[i];
    }
  };

  const int t0 = g * 16;
  load_tile(t0);
  write_tile(0);
  __syncthreads();

  for (int t = 0; t < 16; ++t) {
    const int cur = t & 1;
    const char* lKc = gregion + cur * 32768;
    const char* lVc = lKc + 16384;

    // T14: issue next tile's global loads early; LDS-write to the other buffer later
    if (t < 15) load_tile(t0 + t + 1);

    f32x16 sc[2] = {};
    __builtin_amdgcn_s_setprio(1);
#pragma unroll
    for (int ks = 0; ks < 8; ++ks) {
#pragma unroll
      for (int T = 0; T < 2; ++T) {
        int row = T * 32 + l31;
        bf16x8 kf = *(const bf16x8*)(lKc + ((row * 256 + ks * 32 + hi * 16) ^ ((row & 15) << 4)));
        sc[T] = __builtin_amdgcn_mfma_f32_32x32x16_bf16(kf, qf[ks], sc[T], 0, 0, 0);
      }
    }
    __builtin_amdgcn_s_setprio(0);

    float pmax = sc[0][0];
#pragma unroll
    for (int r = 1; r < 16; ++r) pmax = fmaxf(pmax, sc[0][r]);
#pragma unroll
    for (int r = 0; r < 16; ++r) pmax = fmaxf(pmax, sc[1][r]);
    pmax = fmaxf(pmax, __shfl_xor(pmax, 32));
    if (__any(pmax > mrun + 8.f)) {   // T13 defer-max
      float mn = fmaxf(mrun, pmax);
      float alpha = __expf(mrun - mn);
      mrun = mn;
      lrun *= alpha;
#pragma unroll
      for (int dt = 0; dt < 4; ++dt)
#pragma unroll
        for (int r = 0; r < 16; ++r) o[dt][r] *= alpha;
    }
    float rs = 0.f;
#pragma unroll
    for (int T = 0; T < 2; ++T)
#pragma unroll
      for (int r = 0; r < 16; ++r) {
        float p = __expf(sc[T][r] - mrun);
        sc[T][r] = p;
        rs += p;
      }
    rs += __shfl_xor(rs, 32);
    lrun += rs;

    bf16x8 pf[4];
#pragma unroll
    for (int T = 0; T < 2; ++T) {
#pragma unroll
      for (int gg = 0; gg < 2; ++gg) {
        u32 a0 = cvtpk(sc[T][8 * gg + 0], sc[T][8 * gg + 1]);
        u32 a1 = cvtpk(sc[T][8 * gg + 2], sc[T][8 * gg + 3]);
        u32 a2 = cvtpk(sc[T][8 * gg + 4], sc[T][8 * gg + 5]);
        u32 a3 = cvtpk(sc[T][8 * gg + 6], sc[T][8 * gg + 7]);
        u32 x0 = (u32)__shfl_xor((int)a0, 32);
        u32 x1 = (u32)__shfl_xor((int)a1, 32);
        u32 x2 = (u32)__shfl_xor((int)a2, 32);
        u32 x3 = (u32)__shfl_xor((int)a3, 32);
        u32 s0 = hi ? x2 : a0;
        u32 s1 = hi ? x3 : a1;
        u32 s2 = hi ? a2 : x0;
        u32 s3 = hi ? a3 : x1;
        u32x4 w = {s0, s1, s2, s3};
        pf[T * 2 + gg] = __builtin_bit_cast(bf16x8, w);
      }
    }

    __builtin_amdgcn_s_setprio(1);
#pragma unroll
    for (int ks2 = 0; ks2 < 4; ++ks2) {
#pragma unroll
      for (int dt = 0; dt < 4; ++dt) {
        int row = dt * 32 + l31;
        bf16x8 vf = *(const bf16x8*)(lVc + ((row * 128 + ks2 * 32 + hi * 16) ^ ((row & 7) << 4)));
        o[dt] = __builtin_amdgcn_mfma_f32_32x32x16_bf16(vf, pf[ks2], o[dt], 0, 0, 0);
      }
    }
    __builtin_amdgcn_s_setprio(0);

    // write next tile into the other buffer (its readers finished last iteration)
    if (t < 15) write_tile(cur ^ 1);
    __syncthreads();
  }

  // ---- exact flash-merge of the two kv-half partials ----
  float2* mlb = (float2*)lds;  // overlays group0 region; ordered by barriers below
  if (g == 1) {
    char* myp = lds + 65536 + wq * 8192;   // group1 region reused for bf16 partials
#pragma unroll
    for (int dt = 0; dt < 4; ++dt)
#pragma unroll
      for (int t = 0; t < 8; ++t)
        *(u32*)(myp + (dt * 8 + t) * 256 + lane * 4) = cvtpk(o[dt][2 * t], o[dt][2 * t + 1]);
    if (!hi) mlb[wq * 32 + l31] = float2{mrun, lrun};
  }
  __syncthreads();
  float inv = 0.f;
  if (g == 0) {
    float2 ml1 = mlb[wq * 32 + l31];
    float m = fmaxf(mrun, ml1.x);
    float a0 = __expf(mrun - m), a1 = __expf(ml1.x - m);
    float lt = lrun * a0 + ml1.y * a1;
    inv = 1.0f / lt;
    const char* myp = lds + 65536 + wq * 8192;
#pragma unroll
    for (int dt = 0; dt < 4; ++dt)
#pragma unroll
      for (int t = 0; t < 8; ++t) {
        u32 w = *(const u32*)(myp + (dt * 8 + t) * 256 + lane * 4);
        float plo = bf2f((u16)(w & 0xffffu));
        float phi = bf2f((u16)(w >> 16));
        o[dt][2 * t]     = o[dt][2 * t] * a0 + plo * a1;
        o[dt][2 * t + 1] = o[dt][2 * t + 1] * a0 + phi * a1;
      }
  }
  __syncthreads();  // mlb reads done before group0 transpose overwrites its region

  if (g == 0) {
    // epilogue: O^T -> O via per-wave LDS region (8KB each), then coalesced stores
    char* myreg = lds + wq * 8192;  // [32 q][128 d] bf16, XOR (q&15)<<4 on byte-in-row
#pragma unroll
    for (int dt = 0; dt < 4; ++dt)
#pragma unroll
      for (int t = 0; t < 8; ++t) {
        u32 w = cvtpk(o[dt][2 * t] * inv, o[dt][2 * t + 1] * inv);
        int d0 = dt * 32 + 2 * (t & 1) + 8 * (t >> 1) + 4 * hi;
        *(u32*)(myreg + ((l31 * 256 + d0 * 2) ^ ((l31 & 15) << 4))) = w;
      }
    asm volatile("s_waitcnt lgkmcnt(0)");
    {
      int q = lane >> 1, hf = lane & 1;
      int srow = qt * 256 + wq * 32 + q;
      u16* orow = Ob + ((size_t)(b * S_ + srow)) * HID_ + h * 128 + hf * 64;
#pragma unroll
      for (int i = 0; i < 8; ++i) {
        bf16x8 vv = *(const bf16x8*)(myreg + ((q * 256 + hf * 128 + i * 16) ^ ((q & 15) << 4)));
        *(bf16x8*)(orow + i * 8) = vv;
      }
    }
  }
}

extern "C" void kernel_launch(void* const* d_in, const int* in_sizes, int n_in,
                              void* d_out, int out_size, void* d_ws, size_t ws_size,
                              hipStream_t stream) {
  const float* hs = (const float*)d_in[0];
  const float* cosb = (const float*)d_in[1];
  const float* sinb = (const float*)d_in[2];
  const float* w_qkv = (const float*)d_in[3];
  const float* b_qkv = (const float*)d_in[4];
  const float* w_o = (const float*)d_in[5];
  const float* b_o = (const float*)d_in[6];
  float* out = (float*)d_out;

  char* ws = (char*)d_ws;
  u16* Xb    = (u16*)ws;                          // 16,777,216 B (reused as attn_out)
  u16* Wqkvb = (u16*)(ws + 16777216);             // 12,582,912 B
  u16* Wob   = (u16*)(ws + 29360128);             //  8,388,608 B
  u16* qkvb  = (u16*)(ws + 37748736);             // 25,165,824 B (bf16)
  u16* Qb    = (u16*)(ws + 62914560);             // 16,777,216 B
  u16* Kb    = (u16*)(ws + 79691776);             //  4,194,304 B
  u16* Vt    = (u16*)(ws + 83886080);             //  4,194,304 B  (total 88,080,384 B)
  u16* Ob = Xb;

  hipLaunchKernelGGL(k_cvt3, dim3(2048), dim3(256), 0, stream,
                     hs, Xb, (B_ * S_ * HID_) / 8,
                     w_qkv, Wqkvb, (NQKV_ * HID_) / 8,
                     w_o, Wob, (HID_ * HID_) / 8);
  hipLaunchKernelGGL((k_gemm8p<256, u16>), dim3(NQKV_ / 256, (B_ * S_) / 256), dim3(512), 0, stream,
                     Xb, Wqkvb, b_qkv, qkvb, B_ * S_, NQKV_, HID_);
  hipLaunchKernelGGL(k_rope_split, dim3(B_ * S_), dim3(256), 0, stream, qkvb, cosb, sinb, Qb, Kb, Vt);
  hipLaunchKernelGGL(k_attn, dim3(S_ / 256, B_ * H_), dim3(1024), 0, stream, Qb, Kb, Vt, Ob);
  hipLaunchKernelGGL((k_gemm8p<128, float>), dim3(HID_ / 256, (B_ * S_) / 128), dim3(512), 0, stream,
                     Ob, Wob, b_o, out, B_ * S_, HID_, HID_);
}

// Round 15
// 241.110 us; speedup vs baseline: 1.8027x; 1.8027x over previous
//
#include <hip/hip_runtime.h>
#include <hip/hip_bf16.h>
#include <stdint.h>

typedef __bf16 bf16x8 __attribute__((ext_vector_type(8)));
typedef float f32x4 __attribute__((ext_vector_type(4)));
typedef float f32x16 __attribute__((ext_vector_type(16)));
typedef float f32x4v __attribute__((ext_vector_type(4)));
typedef unsigned short u16;
typedef unsigned int u32;
typedef u16 u16x8 __attribute__((ext_vector_type(8)));
typedef u32 u32x4 __attribute__((ext_vector_type(4)));

#define B_ 2
#define S_ 2048
#define HID_ 2048
#define H_ 16
#define HK_ 4
#define D_ 128
#define NQKV_ 3072

__device__ __forceinline__ u16 f2bf(float f) {
  u32 u = __builtin_bit_cast(u32, f);
  u32 r = (u + 0x7fffu + ((u >> 16) & 1u)) >> 16;
  return (u16)r;
}
__device__ __forceinline__ float bf2f(u16 v) {
  u32 u = ((u32)v) << 16;
  return __builtin_bit_cast(float, u);
}
__device__ __forceinline__ u32 cvtpk(float lo, float hi) {
  u32 r;
  asm("v_cvt_pk_bf16_f32 %0, %1, %2" : "=v"(r) : "v"(lo), "v"(hi));
  return r;
}
__device__ __forceinline__ void gload_lds16(const void* g, void* l) {
  __builtin_amdgcn_global_load_lds((const __attribute__((address_space(1))) void*)g,
                                   (__attribute__((address_space(3))) void*)l, 16, 0, 0);
}

// ---------------- fused f32 -> bf16 convert for 3 buffers ----------------
__global__ __launch_bounds__(256) void k_cvt3(const float* __restrict__ a, u16* __restrict__ oa, int na,
                                              const float* __restrict__ b, u16* __restrict__ ob, int nb,
                                              const float* __restrict__ c, u16* __restrict__ oc, int nc) {
  int total = na + nb + nc;
  for (int i = blockIdx.x * 256 + threadIdx.x; i < total; i += gridDim.x * 256) {
    const float* src;
    u16* dst;
    int j = i;
    if (j < na) { src = a; dst = oa; }
    else if (j < na + nb) { j -= na; src = b; dst = ob; }
    else { j -= na + nb; src = c; dst = oc; }
    const f32x4v* p = (const f32x4v*)(src + (size_t)j * 8);
    f32x4v x = p[0], y = p[1];
    u16x8 w;
    w[0] = f2bf(x[0]); w[1] = f2bf(x[1]); w[2] = f2bf(x[2]); w[3] = f2bf(x[3]);
    w[4] = f2bf(y[0]); w[5] = f2bf(y[1]); w[6] = f2bf(y[2]); w[7] = f2bf(y[3]);
    *(u16x8*)(dst + (size_t)j * 8) = w;
  }
}

// ---------------- 8-phase deep-pipelined GEMM: C = A[M][K] . B[N][K]^T + bias ----
// T1: XCD-aware bijective block swizzle. FUSE: rope fused into epilogue for Q/K blocks.
template <int ISSUES>
__device__ __forceinline__ void stage_half(const u16* __restrict__ src, int K, char* ldsb, int tid) {
#pragma unroll
  for (int i = 0; i < ISSUES; ++i) {
    int off = i * 8192 + tid * 16;
    int r = off >> 7, cb = off & 127;
    int scb = cb ^ ((r & 7) << 4);
    gload_lds16((const char*)(src + (size_t)r * K) + scb, ldsb + i * 8192 + (tid & ~63) * 16);
  }
}

template <int BM, typename CT, bool FUSE>
__global__ __launch_bounds__(512, 1) void k_gemm8p(const u16* __restrict__ A, const u16* __restrict__ Bm,
                                                   const float* __restrict__ bias, CT* __restrict__ C,
                                                   int M, int N, int K,
                                                   const float* __restrict__ cosb,
                                                   const float* __restrict__ sinb,
                                                   u16* __restrict__ Qp, u16* __restrict__ Kp) {
  constexpr int HAR = BM / 2;            // rows per A half-tile
  constexpr int AHB = HAR * 128;         // bytes per A half-tile
  constexpr int AISS = AHB / 8192;       // gload issues per A half
  constexpr int MREP = BM / 32;          // 16-row frags per wave
  constexpr int MQ = MREP / 4;           // m-frags per phase
  constexpr int DB = 2 * AHB + 32768;    // dbuf stride
  __shared__ __attribute__((aligned(16))) char lds[2 * DB];
  const int tid = threadIdx.x, lane = tid & 63;
  const int wid = tid >> 6, wm = wid >> 2, wn = wid & 3;
  const int l15 = lane & 15, l4 = lane >> 4;
  // T1 swizzle: each XCD gets a contiguous chunk of tile space
  const int nwg = gridDim.x * gridDim.y;
  const int bid = blockIdx.y * gridDim.x + blockIdx.x;
  const int wgid = (bid & 7) * (nwg >> 3) + (bid >> 3);
  const int bx = wgid % gridDim.x, by = wgid / gridDim.x;
  const int row0 = by * BM, col0 = bx * 256;
  const int NT = K >> 6;

  f32x4 acc[MREP][4] = {};

  auto stageA = [&](int t, int h) {
    stage_half<AISS>(A + (size_t)(row0 + h * HAR) * K + t * 64, K, lds + (t & 1) * DB + h * AHB, tid);
  };
  auto stageB = [&](int t, int h) {
    stage_half<2>(Bm + (size_t)(col0 + h * 128) * K + t * 64, K, lds + (t & 1) * DB + 2 * AHB + h * 16384, tid);
  };

  stageA(0, 0); stageA(0, 1); stageB(0, 0); stageB(0, 1);
  if (NT > 1) { stageB(1, 0); stageB(1, 1); }
  if (NT > 1) asm volatile("s_waitcnt vmcnt(4)" ::: "memory");
  else        asm volatile("s_waitcnt vmcnt(0)" ::: "memory");
  __builtin_amdgcn_s_barrier();

  const char* myA = lds + wm * AHB;
  const char* myB = lds + 2 * AHB + (wn >> 1) * 16384;
  const int rBb = (wn & 1) * 64;

  for (int t = 0; t < NT; ++t) {
    const int d = t & 1;
    const char* Ab = myA + d * DB;
    const char* Bb = myB + d * DB;
    bf16x8 bfr[4][2];
#pragma unroll
    for (int j = 0; j < 4; ++j) {
      if (j == 0) {
#pragma unroll
        for (int n = 0; n < 4; ++n)
#pragma unroll
          for (int ks = 0; ks < 2; ++ks) {
            int r = rBb + n * 16 + l15;
            bfr[n][ks] = *(const bf16x8*)(Bb + r * 128 + ((ks * 64 + l4 * 16) ^ ((r & 7) << 4)));
          }
      }
      bf16x8 afr[MQ][2];
#pragma unroll
      for (int mq = 0; mq < MQ; ++mq)
#pragma unroll
        for (int ks = 0; ks < 2; ++ks) {
          int r = (j * MQ + mq) * 16 + l15;
          afr[mq][ks] = *(const bf16x8*)(Ab + r * 128 + ((ks * 64 + l4 * 16) ^ ((r & 7) << 4)));
        }
      if (j == 0) { if (t + 1 < NT) stageA(t + 1, 0); }
      else if (j == 1) { if (t + 1 < NT) stageA(t + 1, 1); }
      else if (j == 2) { if (t + 2 < NT) stageB(t + 2, 0); }
      else {
        if (t + 2 < NT) { stageB(t + 2, 1); asm volatile("s_waitcnt vmcnt(4)" ::: "memory"); }
        else             asm volatile("s_waitcnt vmcnt(0)" ::: "memory");
      }
      __builtin_amdgcn_s_barrier();
      asm volatile("s_waitcnt lgkmcnt(0)" ::: "memory");
      __builtin_amdgcn_s_setprio(1);
#pragma unroll
      for (int mq = 0; mq < MQ; ++mq)
#pragma unroll
        for (int ks = 0; ks < 2; ++ks)
#pragma unroll
          for (int n = 0; n < 4; ++n)
            acc[j * MQ + mq][n] =
                __builtin_amdgcn_mfma_f32_16x16x32_bf16(afr[mq][ks], bfr[n][ks], acc[j * MQ + mq][n], 0, 0, 0);
      __builtin_amdgcn_s_setprio(0);
      __builtin_amdgcn_s_barrier();
    }
  }

  bool fusedQK = false;
  if constexpr (FUSE) fusedQK = (col0 < (H_ + HK_) * D_);  // Q or K block (2 heads, uniform)
  if (fusedQK) {
    // rope fused epilogue: per 16-row stripe m, exchange through LDS (f32, stride 264)
    float* ex = (float*)lds;             // [32 rows][264] f32 = 33.8 KB
    const int hg0 = col0 >> 7;           // first head-group index (even)
    const bool isq = hg0 < H_;
    const float rsc = isq ? 0.08838834764831845f : 1.0f;
    u16* dstb = isq ? Qp : Kp;
    const int hbase = isq ? hg0 : (hg0 - H_);
    const int HN = isq ? H_ : HK_;
    const int r = tid >> 4, p = tid & 15;          // consumer mapping
    const int hh = p >> 3, d0 = (p & 7) * 8;
    const int rr = r & 15, wmr = r >> 4;
#pragma unroll 1
    for (int m = 0; m < MREP; ++m) {
#pragma unroll
      for (int n = 0; n < 4; ++n) {
        int colw = wn * 64 + n * 16 + l15;
        float bv = bias[col0 + colw];
#pragma unroll
        for (int r2 = 0; r2 < 4; ++r2)
          ex[(wm * 16 + l4 * 4 + r2) * 264 + colw] = acc[m][n][r2] + bv;
      }
      __syncthreads();
      {
        int grow = row0 + wmr * 128 + m * 16 + rr;
        int bb = grow >> 11, ss = grow & 2047;
        size_t cs = ((size_t)bb * S_ + ss) * D_;
        const float* exr = ex + (wmr * 16 + rr) * 264 + hh * 128;
        f32x4 lo0 = *(const f32x4*)(exr + d0);
        f32x4 lo1 = *(const f32x4*)(exr + d0 + 4);
        f32x4 hi0 = *(const f32x4*)(exr + 64 + d0);
        f32x4 hi1 = *(const f32x4*)(exr + 64 + d0 + 4);
        u16x8 y1, y2;
#pragma unroll
        for (int i = 0; i < 8; ++i) {
          float lo = (i < 4) ? lo0[i] : lo1[i - 4];
          float hi2 = (i < 4) ? hi0[i] : hi1[i - 4];
          float c1 = cosb[cs + d0 + i], s1 = sinb[cs + d0 + i];
          float c2 = cosb[cs + 64 + d0 + i], s2 = sinb[cs + 64 + d0 + i];
          y1[i] = f2bf((lo * c1 - hi2 * s1) * rsc);
          y2[i] = f2bf((hi2 * c2 + lo * s2) * rsc);
        }
        u16* drow = dstb + (((size_t)(bb * HN + hbase + hh)) * S_ + ss) * D_;
        *(u16x8*)(drow + d0) = y1;
        *(u16x8*)(drow + d0 + 64) = y2;
      }
      __syncthreads();
    }
  } else {
#pragma unroll
    for (int m = 0; m < MREP; ++m) {
      int grow = row0 + wm * HAR + m * 16 + l4 * 4;
#pragma unroll
      for (int n = 0; n < 4; ++n) {
        int gcol = col0 + wn * 64 + n * 16 + l15;
        float bv = bias[gcol];
#pragma unroll
        for (int r2 = 0; r2 < 4; ++r2) {
          float v = acc[m][n][r2] + bv;
          if constexpr (sizeof(CT) == 2) C[(size_t)(grow + r2) * N + gcol] = (CT)f2bf(v);
          else                           C[(size_t)(grow + r2) * N + gcol] = v;
        }
      }
    }
  }
}

// ---------------- V split/transpose only (Q/K handled in GEMM epilogue) ----------------
__global__ __launch_bounds__(128) void k_vsplit(const u16* __restrict__ qkv, u16* __restrict__ Vt) {
  const int bs = blockIdx.x;
  const int b = bs >> 11, s = bs & 2047;
  const u16* src = qkv + (size_t)bs * NQKV_ + (H_ + HK_) * D_;
  for (int j = threadIdx.x; j < HK_ * D_; j += 128) {
    int hk = j >> 7, d = j & 127;
    Vt[((size_t)(b * HK_ + hk) * D_ + d) * S_ + s] = src[j];
  }
}

// ---------------- flash attention (R7 known-good): 8 waves x 32 q-rows, 32x32 MFMA,
//                  swapped QK^T, in-register softmax, O^T = V^T . P^T,
//                  LDS double-buffer, one barrier per kv-tile ----------------
__global__ __launch_bounds__(512, 2) void k_attn(const u16* __restrict__ Qb, const u16* __restrict__ Kb,
                                                 const u16* __restrict__ Vt, u16* __restrict__ Ob) {
  __shared__ __attribute__((aligned(16))) char lds[65536];
  const int qt = blockIdx.x;  // 0..7
  const int bh = blockIdx.y;  // 0..31
  const int b = bh >> 4, h = bh & 15, hk = h >> 2;
  const int tid = threadIdx.x, lane = tid & 63, wid = tid >> 6;
  const int l31 = lane & 31, hi = lane >> 5;

  const int qrow = qt * 256 + wid * 32 + l31;
  const u16* qptr = Qb + ((size_t)(b * H_ + h) * S_ + qrow) * D_;
  bf16x8 qf[8];
#pragma unroll
  for (int ks = 0; ks < 8; ++ks) qf[ks] = *(const bf16x8*)(qptr + ks * 16 + hi * 8);

  const u16* kbase = Kb + (size_t)(b * HK_ + hk) * S_ * D_;
  const u16* vbase = Vt + (size_t)(b * HK_ + hk) * D_ * S_;

  int krow[2], kc[2], vrow[2], vc[2];
#pragma unroll
  for (int i = 0; i < 2; ++i) {
    int s = tid + i * 512;
    krow[i] = s >> 4; kc[i] = s & 15;
    vrow[i] = s >> 3; vc[i] = s & 7;
  }

  f32x16 o[4] = {};
  float mrun = -1e30f, lrun = 0.f;

  bf16x8 kreg[2], vreg[2];
#pragma unroll
  for (int i = 0; i < 2; ++i) {
    kreg[i] = *(const bf16x8*)(kbase + (size_t)krow[i] * D_ + kc[i] * 8);
    vreg[i] = *(const bf16x8*)(vbase + (size_t)vrow[i] * S_ + vc[i] * 8);
  }
#pragma unroll
  for (int i = 0; i < 2; ++i) {
    *(bf16x8*)(lds + ((krow[i] * 256 + kc[i] * 16) ^ ((krow[i] & 15) << 4))) = kreg[i];
    *(bf16x8*)(lds + 16384 + ((vrow[i] * 128 + vc[i] * 16) ^ ((vrow[i] & 7) << 4))) = vreg[i];
  }
  __syncthreads();

  for (int kt = 0; kt < 32; ++kt) {
    const int cur = kt & 1;
    const char* lKc = lds + cur * 32768;
    const char* lVc = lKc + 16384;

    if (kt < 31) {
#pragma unroll
      for (int i = 0; i < 2; ++i) {
        kreg[i] = *(const bf16x8*)(kbase + (size_t)((kt + 1) * 64 + krow[i]) * D_ + kc[i] * 8);
        vreg[i] = *(const bf16x8*)(vbase + (size_t)vrow[i] * S_ + (kt + 1) * 64 + vc[i] * 8);
      }
    }

    f32x16 sc[2] = {};
    __builtin_amdgcn_s_setprio(1);
#pragma unroll
    for (int ks = 0; ks < 8; ++ks) {
#pragma unroll
      for (int T = 0; T < 2; ++T) {
        int row = T * 32 + l31;
        bf16x8 kf = *(const bf16x8*)(lKc + ((row * 256 + ks * 32 + hi * 16) ^ ((row & 15) << 4)));
        sc[T] = __builtin_amdgcn_mfma_f32_32x32x16_bf16(kf, qf[ks], sc[T], 0, 0, 0);
      }
    }
    __builtin_amdgcn_s_setprio(0);

    float pmax = sc[0][0];
#pragma unroll
    for (int r = 1; r < 16; ++r) pmax = fmaxf(pmax, sc[0][r]);
#pragma unroll
    for (int r = 0; r < 16; ++r) pmax = fmaxf(pmax, sc[1][r]);
    pmax = fmaxf(pmax, __shfl_xor(pmax, 32));
    if (__any(pmax > mrun + 8.f)) {   // T13 defer-max
      float mn = fmaxf(mrun, pmax);
      float alpha = __expf(mrun - mn);
      mrun = mn;
      lrun *= alpha;
#pragma unroll
      for (int dt = 0; dt < 4; ++dt)
#pragma unroll
        for (int r = 0; r < 16; ++r) o[dt][r] *= alpha;
    }
    float rs = 0.f;
#pragma unroll
    for (int T = 0; T < 2; ++T)
#pragma unroll
      for (int r = 0; r < 16; ++r) {
        float p = __expf(sc[T][r] - mrun);
        sc[T][r] = p;
        rs += p;
      }
    rs += __shfl_xor(rs, 32);
    lrun += rs;

    bf16x8 pf[4];
#pragma unroll
    for (int T = 0; T < 2; ++T) {
#pragma unroll
      for (int g = 0; g < 2; ++g) {
        u32 a0 = cvtpk(sc[T][8 * g + 0], sc[T][8 * g + 1]);
        u32 a1 = cvtpk(sc[T][8 * g + 2], sc[T][8 * g + 3]);
        u32 a2 = cvtpk(sc[T][8 * g + 4], sc[T][8 * g + 5]);
        u32 a3 = cvtpk(sc[T][8 * g + 6], sc[T][8 * g + 7]);
        u32 x0 = (u32)__shfl_xor((int)a0, 32);
        u32 x1 = (u32)__shfl_xor((int)a1, 32);
        u32 x2 = (u32)__shfl_xor((int)a2, 32);
        u32 x3 = (u32)__shfl_xor((int)a3, 32);
        u32 s0 = hi ? x2 : a0;
        u32 s1 = hi ? x3 : a1;
        u32 s2 = hi ? a2 : x0;
        u32 s3 = hi ? a3 : x1;
        u32x4 w = {s0, s1, s2, s3};
        pf[T * 2 + g] = __builtin_bit_cast(bf16x8, w);
      }
    }

    __builtin_amdgcn_s_setprio(1);
#pragma unroll
    for (int ks2 = 0; ks2 < 4; ++ks2) {
#pragma unroll
      for (int dt = 0; dt < 4; ++dt) {
        int row = dt * 32 + l31;
        bf16x8 vf = *(const bf16x8*)(lVc + ((row * 128 + ks2 * 32 + hi * 16) ^ ((row & 7) << 4)));
        o[dt] = __builtin_amdgcn_mfma_f32_32x32x16_bf16(vf, pf[ks2], o[dt], 0, 0, 0);
      }
    }
    __builtin_amdgcn_s_setprio(0);

    if (kt < 31) {
      char* nK = lds + (cur ^ 1) * 32768;
      char* nV = nK + 16384;
#pragma unroll
      for (int i = 0; i < 2; ++i) {
        *(bf16x8*)(nK + ((krow[i] * 256 + kc[i] * 16) ^ ((krow[i] & 15) << 4))) = kreg[i];
        *(bf16x8*)(nV + ((vrow[i] * 128 + vc[i] * 16) ^ ((vrow[i] & 7) << 4))) = vreg[i];
      }
    }
    __syncthreads();
  }

  // epilogue: O^T -> O via per-wave LDS region (8KB each), then coalesced stores
  float inv = 1.0f / lrun;
  char* myreg = lds + wid * 8192;  // [32 q][128 d] bf16, XOR (q&15)<<4 on byte-in-row
#pragma unroll
  for (int dt = 0; dt < 4; ++dt)
#pragma unroll
    for (int t = 0; t < 8; ++t) {
      u32 w = cvtpk(o[dt][2 * t] * inv, o[dt][2 * t + 1] * inv);
      int d0 = dt * 32 + 2 * (t & 1) + 8 * (t >> 1) + 4 * hi;
      *(u32*)(myreg + ((l31 * 256 + d0 * 2) ^ ((l31 & 15) << 4))) = w;
    }
  asm volatile("s_waitcnt lgkmcnt(0)");
  {
    int q = lane >> 1, hf = lane & 1;
    int srow = qt * 256 + wid * 32 + q;
    u16* orow = Ob + ((size_t)(b * S_ + srow)) * HID_ + h * 128 + hf * 64;
#pragma unroll
    for (int i = 0; i < 8; ++i) {
      bf16x8 vv = *(const bf16x8*)(myreg + ((q * 256 + hf * 128 + i * 16) ^ ((q & 15) << 4)));
      *(bf16x8*)(orow + i * 8) = vv;
    }
  }
}

extern "C" void kernel_launch(void* const* d_in, const int* in_sizes, int n_in,
                              void* d_out, int out_size, void* d_ws, size_t ws_size,
                              hipStream_t stream) {
  const float* hs = (const float*)d_in[0];
  const float* cosb = (const float*)d_in[1];
  const float* sinb = (const float*)d_in[2];
  const float* w_qkv = (const float*)d_in[3];
  const float* b_qkv = (const float*)d_in[4];
  const float* w_o = (const float*)d_in[5];
  const float* b_o = (const float*)d_in[6];
  float* out = (float*)d_out;

  char* ws = (char*)d_ws;
  u16* Xb    = (u16*)ws;                          // 16,777,216 B (reused as attn_out)
  u16* Wqkvb = (u16*)(ws + 16777216);             // 12,582,912 B
  u16* Wob   = (u16*)(ws + 29360128);             //  8,388,608 B
  u16* qkvb  = (u16*)(ws + 37748736);             // 25,165,824 B (V cols only now)
  u16* Qb    = (u16*)(ws + 62914560);             // 16,777,216 B
  u16* Kb    = (u16*)(ws + 79691776);             //  4,194,304 B
  u16* Vt    = (u16*)(ws + 83886080);             //  4,194,304 B  (total 88,080,384 B)
  u16* Ob = Xb;

  hipLaunchKernelGGL(k_cvt3, dim3(2048), dim3(256), 0, stream,
                     hs, Xb, (B_ * S_ * HID_) / 8,
                     w_qkv, Wqkvb, (NQKV_ * HID_) / 8,
                     w_o, Wob, (HID_ * HID_) / 8);
  hipLaunchKernelGGL((k_gemm8p<256, u16, true>), dim3(NQKV_ / 256, (B_ * S_) / 256), dim3(512), 0, stream,
                     Xb, Wqkvb, b_qkv, qkvb, B_ * S_, NQKV_, HID_, cosb, sinb, Qb, Kb);
  hipLaunchKernelGGL(k_vsplit, dim3(B_ * S_), dim3(128), 0, stream, qkvb, Vt);
  hipLaunchKernelGGL(k_attn, dim3(S_ / 256, B_ * H_), dim3(512), 0, stream, Qb, Kb, Vt, Ob);
  hipLaunchKernelGGL((k_gemm8p<128, float, false>), dim3(HID_ / 256, (B_ * S_) / 128), dim3(512), 0, stream,
                     Ob, Wob, b_o, out, B_ * S_, HID_, HID_, nullptr, nullptr, nullptr, nullptr);
}

// Round 16
// 230.193 us; speedup vs baseline: 1.8882x; 1.0474x over previous
//
#include <hip/hip_runtime.h>
#include <hip/hip_bf16.h>
#include <stdint.h>

typedef __bf16 bf16x8 __attribute__((ext_vector_type(8)));
typedef float f32x4 __attribute__((ext_vector_type(4)));
typedef float f32x16 __attribute__((ext_vector_type(16)));
typedef float f32x4v __attribute__((ext_vector_type(4)));
typedef unsigned short u16;
typedef unsigned int u32;
typedef u16 u16x8 __attribute__((ext_vector_type(8)));
typedef u32 u32x4 __attribute__((ext_vector_type(4)));

#define B_ 2
#define S_ 2048
#define HID_ 2048
#define H_ 16
#define HK_ 4
#define D_ 128
#define NQKV_ 3072

__device__ __forceinline__ u16 f2bf(float f) {
  u32 u = __builtin_bit_cast(u32, f);
  u32 r = (u + 0x7fffu + ((u >> 16) & 1u)) >> 16;
  return (u16)r;
}
__device__ __forceinline__ float bf2f(u16 v) {
  u32 u = ((u32)v) << 16;
  return __builtin_bit_cast(float, u);
}
__device__ __forceinline__ u32 cvtpk(float lo, float hi) {
  u32 r;
  asm("v_cvt_pk_bf16_f32 %0, %1, %2" : "=v"(r) : "v"(lo), "v"(hi));
  return r;
}
__device__ __forceinline__ void gload_lds16(const void* g, void* l) {
  __builtin_amdgcn_global_load_lds((const __attribute__((address_space(1))) void*)g,
                                   (__attribute__((address_space(3))) void*)l, 16, 0, 0);
}

// ---------------- fused f32 -> bf16 convert for 3 buffers ----------------
__global__ __launch_bounds__(256) void k_cvt3(const float* __restrict__ a, u16* __restrict__ oa, int na,
                                              const float* __restrict__ b, u16* __restrict__ ob, int nb,
                                              const float* __restrict__ c, u16* __restrict__ oc, int nc) {
  int total = na + nb + nc;
  for (int i = blockIdx.x * 256 + threadIdx.x; i < total; i += gridDim.x * 256) {
    const float* src;
    u16* dst;
    int j = i;
    if (j < na) { src = a; dst = oa; }
    else if (j < na + nb) { j -= na; src = b; dst = ob; }
    else { j -= na + nb; src = c; dst = oc; }
    const f32x4v* p = (const f32x4v*)(src + (size_t)j * 8);
    f32x4v x = p[0], y = p[1];
    u16x8 w;
    w[0] = f2bf(x[0]); w[1] = f2bf(x[1]); w[2] = f2bf(x[2]); w[3] = f2bf(x[3]);
    w[4] = f2bf(y[0]); w[5] = f2bf(y[1]); w[6] = f2bf(y[2]); w[7] = f2bf(y[3]);
    *(u16x8*)(dst + (size_t)j * 8) = w;
  }
}

// ---------------- 8-phase deep-pipelined GEMM: C = A[M][K] . B[N][K]^T + bias ----
// T1: XCD-aware bijective block swizzle (nwg % 8 == 0 for all launches here).
template <int ISSUES>
__device__ __forceinline__ void stage_half(const u16* __restrict__ src, int K, char* ldsb, int tid) {
#pragma unroll
  for (int i = 0; i < ISSUES; ++i) {
    int off = i * 8192 + tid * 16;
    int r = off >> 7, cb = off & 127;
    int scb = cb ^ ((r & 7) << 4);
    gload_lds16((const char*)(src + (size_t)r * K) + scb, ldsb + i * 8192 + (tid & ~63) * 16);
  }
}

template <int BM, typename CT>
__global__ __launch_bounds__(512, 1) void k_gemm8p(const u16* __restrict__ A, const u16* __restrict__ Bm,
                                                   const float* __restrict__ bias, CT* __restrict__ C,
                                                   int M, int N, int K) {
  constexpr int HAR = BM / 2;            // rows per A half-tile
  constexpr int AHB = HAR * 128;         // bytes per A half-tile
  constexpr int AISS = AHB / 8192;       // gload issues per A half
  constexpr int MREP = BM / 32;          // 16-row frags per wave
  constexpr int MQ = MREP / 4;           // m-frags per phase
  constexpr int DB = 2 * AHB + 32768;    // dbuf stride
  __shared__ __attribute__((aligned(16))) char lds[2 * DB];
  const int tid = threadIdx.x, lane = tid & 63;
  const int wid = tid >> 6, wm = wid >> 2, wn = wid & 3;
  const int l15 = lane & 15, l4 = lane >> 4;
  // T1 swizzle: each XCD gets a contiguous chunk of tile space
  const int nwg = gridDim.x * gridDim.y;
  const int bid = blockIdx.y * gridDim.x + blockIdx.x;
  const int wgid = (bid & 7) * (nwg >> 3) + (bid >> 3);
  const int bx = wgid % gridDim.x, by = wgid / gridDim.x;
  const int row0 = by * BM, col0 = bx * 256;
  const int NT = K >> 6;

  f32x4 acc[MREP][4] = {};

  auto stageA = [&](int t, int h) {
    stage_half<AISS>(A + (size_t)(row0 + h * HAR) * K + t * 64, K, lds + (t & 1) * DB + h * AHB, tid);
  };
  auto stageB = [&](int t, int h) {
    stage_half<2>(Bm + (size_t)(col0 + h * 128) * K + t * 64, K, lds + (t & 1) * DB + 2 * AHB + h * 16384, tid);
  };

  stageA(0, 0); stageA(0, 1); stageB(0, 0); stageB(0, 1);
  if (NT > 1) { stageB(1, 0); stageB(1, 1); }
  if (NT > 1) asm volatile("s_waitcnt vmcnt(4)" ::: "memory");
  else        asm volatile("s_waitcnt vmcnt(0)" ::: "memory");
  __builtin_amdgcn_s_barrier();

  const char* myA = lds + wm * AHB;
  const char* myB = lds + 2 * AHB + (wn >> 1) * 16384;
  const int rBb = (wn & 1) * 64;

  for (int t = 0; t < NT; ++t) {
    const int d = t & 1;
    const char* Ab = myA + d * DB;
    const char* Bb = myB + d * DB;
    bf16x8 bfr[4][2];
#pragma unroll
    for (int j = 0; j < 4; ++j) {
      if (j == 0) {
#pragma unroll
        for (int n = 0; n < 4; ++n)
#pragma unroll
          for (int ks = 0; ks < 2; ++ks) {
            int r = rBb + n * 16 + l15;
            bfr[n][ks] = *(const bf16x8*)(Bb + r * 128 + ((ks * 64 + l4 * 16) ^ ((r & 7) << 4)));
          }
      }
      bf16x8 afr[MQ][2];
#pragma unroll
      for (int mq = 0; mq < MQ; ++mq)
#pragma unroll
        for (int ks = 0; ks < 2; ++ks) {
          int r = (j * MQ + mq) * 16 + l15;
          afr[mq][ks] = *(const bf16x8*)(Ab + r * 128 + ((ks * 64 + l4 * 16) ^ ((r & 7) << 4)));
        }
      if (j == 0) { if (t + 1 < NT) stageA(t + 1, 0); }
      else if (j == 1) { if (t + 1 < NT) stageA(t + 1, 1); }
      else if (j == 2) { if (t + 2 < NT) stageB(t + 2, 0); }
      else {
        if (t + 2 < NT) { stageB(t + 2, 1); asm volatile("s_waitcnt vmcnt(4)" ::: "memory"); }
        else             asm volatile("s_waitcnt vmcnt(0)" ::: "memory");
      }
      __builtin_amdgcn_s_barrier();
      asm volatile("s_waitcnt lgkmcnt(0)" ::: "memory");
      __builtin_amdgcn_s_setprio(1);
#pragma unroll
      for (int mq = 0; mq < MQ; ++mq)
#pragma unroll
        for (int ks = 0; ks < 2; ++ks)
#pragma unroll
          for (int n = 0; n < 4; ++n)
            acc[j * MQ + mq][n] =
                __builtin_amdgcn_mfma_f32_16x16x32_bf16(afr[mq][ks], bfr[n][ks], acc[j * MQ + mq][n], 0, 0, 0);
      __builtin_amdgcn_s_setprio(0);
      __builtin_amdgcn_s_barrier();
    }
  }

#pragma unroll
  for (int m = 0; m < MREP; ++m) {
    int grow = row0 + wm * HAR + m * 16 + l4 * 4;
#pragma unroll
    for (int n = 0; n < 4; ++n) {
      int gcol = col0 + wn * 64 + n * 16 + l15;
      float bv = bias[gcol];
#pragma unroll
      for (int r2 = 0; r2 < 4; ++r2) {
        float v = acc[m][n][r2] + bv;
        if constexpr (sizeof(CT) == 2) C[(size_t)(grow + r2) * N + gcol] = (CT)f2bf(v);
        else                           C[(size_t)(grow + r2) * N + gcol] = v;
      }
    }
  }
}

// ---------------- RoPE + split + layout (qkv bf16), vectorized bf16x8 ----------------
__global__ __launch_bounds__(256) void k_rope_split(const u16* __restrict__ qkv,
                                                    const float* __restrict__ cosb,
                                                    const float* __restrict__ sinb,
                                                    u16* __restrict__ Qb, u16* __restrict__ Kb,
                                                    u16* __restrict__ Vt) {
  const int bs = blockIdx.x;
  const int b = bs >> 11, s = bs & 2047;
  const size_t base = (size_t)bs * NQKV_;
  const size_t cs = (size_t)bs * D_;
  const int tid = threadIdx.x;
  const float qscale = 0.08838834764831845f;  // 1/sqrt(128)

  if (tid < 160) {
    const bool isq = tid < 128;
    const int idx = isq ? tid : (tid - 128);
    const int hh = idx >> 3, d0 = (idx & 7) * 8;
    const size_t srcb = base + (isq ? 0 : H_ * D_) + hh * D_;
    bf16x8 x1 = *(const bf16x8*)(qkv + srcb + d0);
    bf16x8 x2 = *(const bf16x8*)(qkv + srcb + d0 + 64);
    u16x8 y1, y2;
    const u16x8 u1 = __builtin_bit_cast(u16x8, x1);
    const u16x8 u2 = __builtin_bit_cast(u16x8, x2);
    const float sc = isq ? qscale : 1.0f;
#pragma unroll
    for (int i = 0; i < 8; ++i) {
      float f1 = bf2f(u1[i]), f2 = bf2f(u2[i]);
      float c1 = cosb[cs + d0 + i], s1 = sinb[cs + d0 + i];
      float c2 = cosb[cs + 64 + d0 + i], s2 = sinb[cs + 64 + d0 + i];
      y1[i] = f2bf((f1 * c1 - f2 * s1) * sc);
      y2[i] = f2bf((f2 * c2 + f1 * s2) * sc);
    }
    size_t o;
    if (isq) o = ((size_t)(b * H_ + hh) * S_ + s) * D_ + d0;
    else     o = ((size_t)(b * HK_ + hh) * S_ + s) * D_ + d0;
    u16* dst = isq ? Qb : Kb;
    *(u16x8*)(dst + o) = y1;
    *(u16x8*)(dst + o + 64) = y2;
  } else if (tid < 224) {
    const int idx = tid - 160;
    const int hk = idx >> 4, d0 = (idx & 15) * 8;
    bf16x8 xv = *(const bf16x8*)(qkv + base + (H_ + HK_) * D_ + hk * D_ + d0);
    const u16x8 uv = __builtin_bit_cast(u16x8, xv);
    u16* vb = Vt + (size_t)(b * HK_ + hk) * D_ * S_ + s;
#pragma unroll
    for (int i = 0; i < 8; ++i) vb[(size_t)(d0 + i) * S_] = uv[i];
  }
}

// ---------------- flash attention (R7 known-good): 8 waves x 32 q-rows, 32x32 MFMA,
//                  swapped QK^T, in-register softmax, O^T = V^T . P^T,
//                  LDS double-buffer, one barrier per kv-tile ----------------
__global__ __launch_bounds__(512, 2) void k_attn(const u16* __restrict__ Qb, const u16* __restrict__ Kb,
                                                 const u16* __restrict__ Vt, u16* __restrict__ Ob) {
  __shared__ __attribute__((aligned(16))) char lds[65536];
  const int qt = blockIdx.x;  // 0..7
  const int bh = blockIdx.y;  // 0..31
  const int b = bh >> 4, h = bh & 15, hk = h >> 2;
  const int tid = threadIdx.x, lane = tid & 63, wid = tid >> 6;
  const int l31 = lane & 31, hi = lane >> 5;

  const int qrow = qt * 256 + wid * 32 + l31;
  const u16* qptr = Qb + ((size_t)(b * H_ + h) * S_ + qrow) * D_;
  bf16x8 qf[8];
#pragma unroll
  for (int ks = 0; ks < 8; ++ks) qf[ks] = *(const bf16x8*)(qptr + ks * 16 + hi * 8);

  const u16* kbase = Kb + (size_t)(b * HK_ + hk) * S_ * D_;
  const u16* vbase = Vt + (size_t)(b * HK_ + hk) * D_ * S_;

  int krow[2], kc[2], vrow[2], vc[2];
#pragma unroll
  for (int i = 0; i < 2; ++i) {
    int s = tid + i * 512;
    krow[i] = s >> 4; kc[i] = s & 15;
    vrow[i] = s >> 3; vc[i] = s & 7;
  }

  f32x16 o[4] = {};
  float mrun = -1e30f, lrun = 0.f;

  bf16x8 kreg[2], vreg[2];
#pragma unroll
  for (int i = 0; i < 2; ++i) {
    kreg[i] = *(const bf16x8*)(kbase + (size_t)krow[i] * D_ + kc[i] * 8);
    vreg[i] = *(const bf16x8*)(vbase + (size_t)vrow[i] * S_ + vc[i] * 8);
  }
#pragma unroll
  for (int i = 0; i < 2; ++i) {
    *(bf16x8*)(lds + ((krow[i] * 256 + kc[i] * 16) ^ ((krow[i] & 15) << 4))) = kreg[i];
    *(bf16x8*)(lds + 16384 + ((vrow[i] * 128 + vc[i] * 16) ^ ((vrow[i] & 7) << 4))) = vreg[i];
  }
  __syncthreads();

  for (int kt = 0; kt < 32; ++kt) {
    const int cur = kt & 1;
    const char* lKc = lds + cur * 32768;
    const char* lVc = lKc + 16384;

    if (kt < 31) {
#pragma unroll
      for (int i = 0; i < 2; ++i) {
        kreg[i] = *(const bf16x8*)(kbase + (size_t)((kt + 1) * 64 + krow[i]) * D_ + kc[i] * 8);
        vreg[i] = *(const bf16x8*)(vbase + (size_t)vrow[i] * S_ + (kt + 1) * 64 + vc[i] * 8);
      }
    }

    f32x16 sc[2] = {};
    __builtin_amdgcn_s_setprio(1);
#pragma unroll
    for (int ks = 0; ks < 8; ++ks) {
#pragma unroll
      for (int T = 0; T < 2; ++T) {
        int row = T * 32 + l31;
        bf16x8 kf = *(const bf16x8*)(lKc + ((row * 256 + ks * 32 + hi * 16) ^ ((row & 15) << 4)));
        sc[T] = __builtin_amdgcn_mfma_f32_32x32x16_bf16(kf, qf[ks], sc[T], 0, 0, 0);
      }
    }
    __builtin_amdgcn_s_setprio(0);

    float pmax = sc[0][0];
#pragma unroll
    for (int r = 1; r < 16; ++r) pmax = fmaxf(pmax, sc[0][r]);
#pragma unroll
    for (int r = 0; r < 16; ++r) pmax = fmaxf(pmax, sc[1][r]);
    pmax = fmaxf(pmax, __shfl_xor(pmax, 32));
    if (__any(pmax > mrun + 8.f)) {   // T13 defer-max
      float mn = fmaxf(mrun, pmax);
      float alpha = __expf(mrun - mn);
      mrun = mn;
      lrun *= alpha;
#pragma unroll
      for (int dt = 0; dt < 4; ++dt)
#pragma unroll
        for (int r = 0; r < 16; ++r) o[dt][r] *= alpha;
    }
    float rs = 0.f;
#pragma unroll
    for (int T = 0; T < 2; ++T)
#pragma unroll
      for (int r = 0; r < 16; ++r) {
        float p = __expf(sc[T][r] - mrun);
        sc[T][r] = p;
        rs += p;
      }
    rs += __shfl_xor(rs, 32);
    lrun += rs;

    bf16x8 pf[4];
#pragma unroll
    for (int T = 0; T < 2; ++T) {
#pragma unroll
      for (int g = 0; g < 2; ++g) {
        u32 a0 = cvtpk(sc[T][8 * g + 0], sc[T][8 * g + 1]);
        u32 a1 = cvtpk(sc[T][8 * g + 2], sc[T][8 * g + 3]);
        u32 a2 = cvtpk(sc[T][8 * g + 4], sc[T][8 * g + 5]);
        u32 a3 = cvtpk(sc[T][8 * g + 6], sc[T][8 * g + 7]);
        u32 x0 = (u32)__shfl_xor((int)a0, 32);
        u32 x1 = (u32)__shfl_xor((int)a1, 32);
        u32 x2 = (u32)__shfl_xor((int)a2, 32);
        u32 x3 = (u32)__shfl_xor((int)a3, 32);
        u32 s0 = hi ? x2 : a0;
        u32 s1 = hi ? x3 : a1;
        u32 s2 = hi ? a2 : x0;
        u32 s3 = hi ? a3 : x1;
        u32x4 w = {s0, s1, s2, s3};
        pf[T * 2 + g] = __builtin_bit_cast(bf16x8, w);
      }
    }

    __builtin_amdgcn_s_setprio(1);
#pragma unroll
    for (int ks2 = 0; ks2 < 4; ++ks2) {
#pragma unroll
      for (int dt = 0; dt < 4; ++dt) {
        int row = dt * 32 + l31;
        bf16x8 vf = *(const bf16x8*)(lVc + ((row * 128 + ks2 * 32 + hi * 16) ^ ((row & 7) << 4)));
        o[dt] = __builtin_amdgcn_mfma_f32_32x32x16_bf16(vf, pf[ks2], o[dt], 0, 0, 0);
      }
    }
    __builtin_amdgcn_s_setprio(0);

    if (kt < 31) {
      char* nK = lds + (cur ^ 1) * 32768;
      char* nV = nK + 16384;
#pragma unroll
      for (int i = 0; i < 2; ++i) {
        *(bf16x8*)(nK + ((krow[i] * 256 + kc[i] * 16) ^ ((krow[i] & 15) << 4))) = kreg[i];
        *(bf16x8*)(nV + ((vrow[i] * 128 + vc[i] * 16) ^ ((vrow[i] & 7) << 4))) = vreg[i];
      }
    }
    __syncthreads();
  }

  // epilogue: O^T -> O via per-wave LDS region (8KB each), then coalesced stores
  float inv = 1.0f / lrun;
  char* myreg = lds + wid * 8192;  // [32 q][128 d] bf16, XOR (q&15)<<4 on byte-in-row
#pragma unroll
  for (int dt = 0; dt < 4; ++dt)
#pragma unroll
    for (int t = 0; t < 8; ++t) {
      u32 w = cvtpk(o[dt][2 * t] * inv, o[dt][2 * t + 1] * inv);
      int d0 = dt * 32 + 2 * (t & 1) + 8 * (t >> 1) + 4 * hi;
      *(u32*)(myreg + ((l31 * 256 + d0 * 2) ^ ((l31 & 15) << 4))) = w;
    }
  asm volatile("s_waitcnt lgkmcnt(0)");
  {
    int q = lane >> 1, hf = lane & 1;
    int srow = qt * 256 + wid * 32 + q;
    u16* orow = Ob + ((size_t)(b * S_ + srow)) * HID_ + h * 128 + hf * 64;
#pragma unroll
    for (int i = 0; i < 8; ++i) {
      bf16x8 vv = *(const bf16x8*)(myreg + ((q * 256 + hf * 128 + i * 16) ^ ((q & 15) << 4)));
      *(bf16x8*)(orow + i * 8) = vv;
    }
  }
}

extern "C" void kernel_launch(void* const* d_in, const int* in_sizes, int n_in,
                              void* d_out, int out_size, void* d_ws, size_t ws_size,
                              hipStream_t stream) {
  const float* hs = (const float*)d_in[0];
  const float* cosb = (const float*)d_in[1];
  const float* sinb = (const float*)d_in[2];
  const float* w_qkv = (const float*)d_in[3];
  const float* b_qkv = (const float*)d_in[4];
  const float* w_o = (const float*)d_in[5];
  const float* b_o = (const float*)d_in[6];
  float* out = (float*)d_out;

  char* ws = (char*)d_ws;
  u16* Xb    = (u16*)ws;                          // 16,777,216 B (reused as attn_out)
  u16* Wqkvb = (u16*)(ws + 16777216);             // 12,582,912 B
  u16* Wob   = (u16*)(ws + 29360128);             //  8,388,608 B
  u16* qkvb  = (u16*)(ws + 37748736);             // 25,165,824 B (bf16)
  u16* Qb    = (u16*)(ws + 62914560);             // 16,777,216 B
  u16* Kb    = (u16*)(ws + 79691776);             //  4,194,304 B
  u16* Vt    = (u16*)(ws + 83886080);             //  4,194,304 B  (total 88,080,384 B)
  u16* Ob = Xb;

  hipLaunchKernelGGL(k_cvt3, dim3(2048), dim3(256), 0, stream,
                     hs, Xb, (B_ * S_ * HID_) / 8,
                     w_qkv, Wqkvb, (NQKV_ * HID_) / 8,
                     w_o, Wob, (HID_ * HID_) / 8);
  hipLaunchKernelGGL((k_gemm8p<128, u16>), dim3(NQKV_ / 256, (B_ * S_) / 128), dim3(512), 0, stream,
                     Xb, Wqkvb, b_qkv, qkvb, B_ * S_, NQKV_, HID_);
  hipLaunchKernelGGL(k_rope_split, dim3(B_ * S_), dim3(256), 0, stream, qkvb, cosb, sinb, Qb, Kb, Vt);
  hipLaunchKernelGGL(k_attn, dim3(S_ / 256, B_ * H_), dim3(512), 0, stream, Qb, Kb, Vt, Ob);
  hipLaunchKernelGGL((k_gemm8p<128, float>), dim3(HID_ / 256, (B_ * S_) / 128), dim3(512), 0, stream,
                     Ob, Wob, b_o, out, B_ * S_, HID_, HID_);
}

// Round 17
// 217.496 us; speedup vs baseline: 1.9985x; 1.0584x over previous
//
#include <hip/hip_runtime.h>
#include <hip/hip_bf16.h>
#include <stdint.h>

typedef __bf16 bf16x8 __attribute__((ext_vector_type(8)));
typedef float f32x4 __attribute__((ext_vector_type(4)));
typedef float f32x16 __attribute__((ext_vector_type(16)));
typedef float f32x4v __attribute__((ext_vector_type(4)));
typedef unsigned short u16;
typedef unsigned int u32;
typedef u16 u16x8 __attribute__((ext_vector_type(8)));
typedef u32 u32x4 __attribute__((ext_vector_type(4)));

#define B_ 2
#define S_ 2048
#define HID_ 2048
#define H_ 16
#define HK_ 4
#define D_ 128
#define NQKV_ 3072

__device__ __forceinline__ u16 f2bf(float f) {
  u32 u = __builtin_bit_cast(u32, f);
  u32 r = (u + 0x7fffu + ((u >> 16) & 1u)) >> 16;
  return (u16)r;
}
__device__ __forceinline__ float bf2f(u16 v) {
  u32 u = ((u32)v) << 16;
  return __builtin_bit_cast(float, u);
}
__device__ __forceinline__ u32 cvtpk(float lo, float hi) {
  u32 r;
  asm("v_cvt_pk_bf16_f32 %0, %1, %2" : "=v"(r) : "v"(lo), "v"(hi));
  return r;
}
__device__ __forceinline__ void gload_lds16(const void* g, void* l) {
  __builtin_amdgcn_global_load_lds((const __attribute__((address_space(1))) void*)g,
                                   (__attribute__((address_space(3))) void*)l, 16, 0, 0);
}

// ---------------- fused f32 -> bf16 convert for 3 buffers ----------------
__global__ __launch_bounds__(256) void k_cvt3(const float* __restrict__ a, u16* __restrict__ oa, int na,
                                              const float* __restrict__ b, u16* __restrict__ ob, int nb,
                                              const float* __restrict__ c, u16* __restrict__ oc, int nc) {
  int total = na + nb + nc;
  for (int i = blockIdx.x * 256 + threadIdx.x; i < total; i += gridDim.x * 256) {
    const float* src;
    u16* dst;
    int j = i;
    if (j < na) { src = a; dst = oa; }
    else if (j < na + nb) { j -= na; src = b; dst = ob; }
    else { j -= na + nb; src = c; dst = oc; }
    const f32x4v* p = (const f32x4v*)(src + (size_t)j * 8);
    f32x4v x = p[0], y = p[1];
    u16x8 w;
    w[0] = f2bf(x[0]); w[1] = f2bf(x[1]); w[2] = f2bf(x[2]); w[3] = f2bf(x[3]);
    w[4] = f2bf(y[0]); w[5] = f2bf(y[1]); w[6] = f2bf(y[2]); w[7] = f2bf(y[3]);
    *(u16x8*)(dst + (size_t)j * 8) = w;
  }
}

// ---------------- 8-phase deep-pipelined GEMM: C = A[M][K] . B[N][K]^T + bias ----
// T1: XCD-aware bijective block swizzle (nwg % 8 == 0 for all launches here).
template <int ISSUES>
__device__ __forceinline__ void stage_half(const u16* __restrict__ src, int K, char* ldsb, int tid) {
#pragma unroll
  for (int i = 0; i < ISSUES; ++i) {
    int off = i * 8192 + tid * 16;
    int r = off >> 7, cb = off & 127;
    int scb = cb ^ ((r & 7) << 4);
    gload_lds16((const char*)(src + (size_t)r * K) + scb, ldsb + i * 8192 + (tid & ~63) * 16);
  }
}

template <int BM, typename CT>
__global__ __launch_bounds__(512, 1) void k_gemm8p(const u16* __restrict__ A, const u16* __restrict__ Bm,
                                                   const float* __restrict__ bias, CT* __restrict__ C,
                                                   int M, int N, int K) {
  constexpr int HAR = BM / 2;            // rows per A half-tile
  constexpr int AHB = HAR * 128;         // bytes per A half-tile
  constexpr int AISS = AHB / 8192;       // gload issues per A half
  constexpr int MREP = BM / 32;          // 16-row frags per wave
  constexpr int MQ = MREP / 4;           // m-frags per phase
  constexpr int DB = 2 * AHB + 32768;    // dbuf stride
  __shared__ __attribute__((aligned(16))) char lds[2 * DB];
  const int tid = threadIdx.x, lane = tid & 63;
  const int wid = tid >> 6, wm = wid >> 2, wn = wid & 3;
  const int l15 = lane & 15, l4 = lane >> 4;
  // T1 swizzle: each XCD gets a contiguous chunk of tile space
  const int nwg = gridDim.x * gridDim.y;
  const int bid = blockIdx.y * gridDim.x + blockIdx.x;
  const int wgid = (bid & 7) * (nwg >> 3) + (bid >> 3);
  const int bx = wgid % gridDim.x, by = wgid / gridDim.x;
  const int row0 = by * BM, col0 = bx * 256;
  const int NT = K >> 6;

  f32x4 acc[MREP][4] = {};

  auto stageA = [&](int t, int h) {
    stage_half<AISS>(A + (size_t)(row0 + h * HAR) * K + t * 64, K, lds + (t & 1) * DB + h * AHB, tid);
  };
  auto stageB = [&](int t, int h) {
    stage_half<2>(Bm + (size_t)(col0 + h * 128) * K + t * 64, K, lds + (t & 1) * DB + 2 * AHB + h * 16384, tid);
  };

  stageA(0, 0); stageA(0, 1); stageB(0, 0); stageB(0, 1);
  if (NT > 1) { stageB(1, 0); stageB(1, 1); }
  if (NT > 1) asm volatile("s_waitcnt vmcnt(4)" ::: "memory");
  else        asm volatile("s_waitcnt vmcnt(0)" ::: "memory");
  __builtin_amdgcn_s_barrier();

  const char* myA = lds + wm * AHB;
  const char* myB = lds + 2 * AHB + (wn >> 1) * 16384;
  const int rBb = (wn & 1) * 64;

  for (int t = 0; t < NT; ++t) {
    const int d = t & 1;
    const char* Ab = myA + d * DB;
    const char* Bb = myB + d * DB;
    bf16x8 bfr[4][2];
#pragma unroll
    for (int j = 0; j < 4; ++j) {
      if (j == 0) {
#pragma unroll
        for (int n = 0; n < 4; ++n)
#pragma unroll
          for (int ks = 0; ks < 2; ++ks) {
            int r = rBb + n * 16 + l15;
            bfr[n][ks] = *(const bf16x8*)(Bb + r * 128 + ((ks * 64 + l4 * 16) ^ ((r & 7) << 4)));
          }
      }
      bf16x8 afr[MQ][2];
#pragma unroll
      for (int mq = 0; mq < MQ; ++mq)
#pragma unroll
        for (int ks = 0; ks < 2; ++ks) {
          int r = (j * MQ + mq) * 16 + l15;
          afr[mq][ks] = *(const bf16x8*)(Ab + r * 128 + ((ks * 64 + l4 * 16) ^ ((r & 7) << 4)));
        }
      if (j == 0) { if (t + 1 < NT) stageA(t + 1, 0); }
      else if (j == 1) { if (t + 1 < NT) stageA(t + 1, 1); }
      else if (j == 2) { if (t + 2 < NT) stageB(t + 2, 0); }
      else {
        if (t + 2 < NT) { stageB(t + 2, 1); asm volatile("s_waitcnt vmcnt(4)" ::: "memory"); }
        else             asm volatile("s_waitcnt vmcnt(0)" ::: "memory");
      }
      __builtin_amdgcn_s_barrier();
      asm volatile("s_waitcnt lgkmcnt(0)" ::: "memory");
      __builtin_amdgcn_s_setprio(1);
#pragma unroll
      for (int mq = 0; mq < MQ; ++mq)
#pragma unroll
        for (int ks = 0; ks < 2; ++ks)
#pragma unroll
          for (int n = 0; n < 4; ++n)
            acc[j * MQ + mq][n] =
                __builtin_amdgcn_mfma_f32_16x16x32_bf16(afr[mq][ks], bfr[n][ks], acc[j * MQ + mq][n], 0, 0, 0);
      __builtin_amdgcn_s_setprio(0);
      __builtin_amdgcn_s_barrier();
    }
  }

#pragma unroll
  for (int m = 0; m < MREP; ++m) {
    int grow = row0 + wm * HAR + m * 16 + l4 * 4;
#pragma unroll
    for (int n = 0; n < 4; ++n) {
      int gcol = col0 + wn * 64 + n * 16 + l15;
      float bv = bias[gcol];
#pragma unroll
      for (int r2 = 0; r2 < 4; ++r2) {
        float v = acc[m][n][r2] + bv;
        if constexpr (sizeof(CT) == 2) C[(size_t)(grow + r2) * N + gcol] = (CT)f2bf(v);
        else                           C[(size_t)(grow + r2) * N + gcol] = v;
      }
    }
  }
}

// ---------------- RoPE + split + layout (qkv bf16), vectorized bf16x8 ----------------
__global__ __launch_bounds__(256) void k_rope_split(const u16* __restrict__ qkv,
                                                    const float* __restrict__ cosb,
                                                    const float* __restrict__ sinb,
                                                    u16* __restrict__ Qb, u16* __restrict__ Kb,
                                                    u16* __restrict__ Vt) {
  const int bs = blockIdx.x;
  const int b = bs >> 11, s = bs & 2047;
  const size_t base = (size_t)bs * NQKV_;
  const size_t cs = (size_t)bs * D_;
  const int tid = threadIdx.x;
  const float qscale = 0.08838834764831845f;  // 1/sqrt(128)

  if (tid < 160) {
    const bool isq = tid < 128;
    const int idx = isq ? tid : (tid - 128);
    const int hh = idx >> 3, d0 = (idx & 7) * 8;
    const size_t srcb = base + (isq ? 0 : H_ * D_) + hh * D_;
    bf16x8 x1 = *(const bf16x8*)(qkv + srcb + d0);
    bf16x8 x2 = *(const bf16x8*)(qkv + srcb + d0 + 64);
    u16x8 y1, y2;
    const u16x8 u1 = __builtin_bit_cast(u16x8, x1);
    const u16x8 u2 = __builtin_bit_cast(u16x8, x2);
    const float sc = isq ? qscale : 1.0f;
#pragma unroll
    for (int i = 0; i < 8; ++i) {
      float f1 = bf2f(u1[i]), f2 = bf2f(u2[i]);
      float c1 = cosb[cs + d0 + i], s1 = sinb[cs + d0 + i];
      float c2 = cosb[cs + 64 + d0 + i], s2 = sinb[cs + 64 + d0 + i];
      y1[i] = f2bf((f1 * c1 - f2 * s1) * sc);
      y2[i] = f2bf((f2 * c2 + f1 * s2) * sc);
    }
    size_t o;
    if (isq) o = ((size_t)(b * H_ + hh) * S_ + s) * D_ + d0;
    else     o = ((size_t)(b * HK_ + hh) * S_ + s) * D_ + d0;
    u16* dst = isq ? Qb : Kb;
    *(u16x8*)(dst + o) = y1;
    *(u16x8*)(dst + o + 64) = y2;
  } else if (tid < 224) {
    const int idx = tid - 160;
    const int hk = idx >> 4, d0 = (idx & 15) * 8;
    bf16x8 xv = *(const bf16x8*)(qkv + base + (H_ + HK_) * D_ + hk * D_ + d0);
    const u16x8 uv = __builtin_bit_cast(u16x8, xv);
    u16* vb = Vt + (size_t)(b * HK_ + hk) * D_ * S_ + s;
#pragma unroll
    for (int i = 0; i < 8; ++i) vb[(size_t)(d0 + i) * S_] = uv[i];
  }
}

// ---------------- flash attention (known-good): 8 waves x 32 q-rows, 32x32 MFMA,
//                  swapped QK^T, in-register softmax, O^T = V^T . P^T,
//                  LDS double-buffer, one barrier per kv-tile ----------------
__global__ __launch_bounds__(512, 2) void k_attn(const u16* __restrict__ Qb, const u16* __restrict__ Kb,
                                                 const u16* __restrict__ Vt, u16* __restrict__ Ob) {
  __shared__ __attribute__((aligned(16))) char lds[65536];
  const int qt = blockIdx.x;  // 0..7
  const int bh = blockIdx.y;  // 0..31
  const int b = bh >> 4, h = bh & 15, hk = h >> 2;
  const int tid = threadIdx.x, lane = tid & 63, wid = tid >> 6;
  const int l31 = lane & 31, hi = lane >> 5;

  const int qrow = qt * 256 + wid * 32 + l31;
  const u16* qptr = Qb + ((size_t)(b * H_ + h) * S_ + qrow) * D_;
  bf16x8 qf[8];
#pragma unroll
  for (int ks = 0; ks < 8; ++ks) qf[ks] = *(const bf16x8*)(qptr + ks * 16 + hi * 8);

  const u16* kbase = Kb + (size_t)(b * HK_ + hk) * S_ * D_;
  const u16* vbase = Vt + (size_t)(b * HK_ + hk) * D_ * S_;

  int krow[2], kc[2], vrow[2], vc[2];
#pragma unroll
  for (int i = 0; i < 2; ++i) {
    int s = tid + i * 512;
    krow[i] = s >> 4; kc[i] = s & 15;
    vrow[i] = s >> 3; vc[i] = s & 7;
  }

  f32x16 o[4] = {};
  float mrun = -1e30f, lrun = 0.f;

  bf16x8 kreg[2], vreg[2];
#pragma unroll
  for (int i = 0; i < 2; ++i) {
    kreg[i] = *(const bf16x8*)(kbase + (size_t)krow[i] * D_ + kc[i] * 8);
    vreg[i] = *(const bf16x8*)(vbase + (size_t)vrow[i] * S_ + vc[i] * 8);
  }
#pragma unroll
  for (int i = 0; i < 2; ++i) {
    *(bf16x8*)(lds + ((krow[i] * 256 + kc[i] * 16) ^ ((krow[i] & 15) << 4))) = kreg[i];
    *(bf16x8*)(lds + 16384 + ((vrow[i] * 128 + vc[i] * 16) ^ ((vrow[i] & 7) << 4))) = vreg[i];
  }
  __syncthreads();

  for (int kt = 0; kt < 32; ++kt) {
    const int cur = kt & 1;
    const char* lKc = lds + cur * 32768;
    const char* lVc = lKc + 16384;

    if (kt < 31) {
#pragma unroll
      for (int i = 0; i < 2; ++i) {
        kreg[i] = *(const bf16x8*)(kbase + (size_t)((kt + 1) * 64 + krow[i]) * D_ + kc[i] * 8);
        vreg[i] = *(const bf16x8*)(vbase + (size_t)vrow[i] * S_ + (kt + 1) * 64 + vc[i] * 8);
      }
    }

    f32x16 sc[2] = {};
    __builtin_amdgcn_s_setprio(1);
#pragma unroll
    for (int ks = 0; ks < 8; ++ks) {
#pragma unroll
      for (int T = 0; T < 2; ++T) {
        int row = T * 32 + l31;
        bf16x8 kf = *(const bf16x8*)(lKc + ((row * 256 + ks * 32 + hi * 16) ^ ((row & 15) << 4)));
        sc[T] = __builtin_amdgcn_mfma_f32_32x32x16_bf16(kf, qf[ks], sc[T], 0, 0, 0);
      }
    }
    __builtin_amdgcn_s_setprio(0);

    float pmax = sc[0][0];
#pragma unroll
    for (int r = 1; r < 16; ++r) pmax = fmaxf(pmax, sc[0][r]);
#pragma unroll
    for (int r = 0; r < 16; ++r) pmax = fmaxf(pmax, sc[1][r]);
    pmax = fmaxf(pmax, __shfl_xor(pmax, 32));
    if (__any(pmax > mrun + 8.f)) {   // T13 defer-max
      float mn = fmaxf(mrun, pmax);
      float alpha = __expf(mrun - mn);
      mrun = mn;
      lrun *= alpha;
#pragma unroll
      for (int dt = 0; dt < 4; ++dt)
#pragma unroll
        for (int r = 0; r < 16; ++r) o[dt][r] *= alpha;
    }
    float rs = 0.f;
#pragma unroll
    for (int T = 0; T < 2; ++T)
#pragma unroll
      for (int r = 0; r < 16; ++r) {
        float p = __expf(sc[T][r] - mrun);
        sc[T][r] = p;
        rs += p;
      }
    rs += __shfl_xor(rs, 32);
    lrun += rs;

    bf16x8 pf[4];
#pragma unroll
    for (int T = 0; T < 2; ++T) {
#pragma unroll
      for (int g = 0; g < 2; ++g) {
        u32 a0 = cvtpk(sc[T][8 * g + 0], sc[T][8 * g + 1]);
        u32 a1 = cvtpk(sc[T][8 * g + 2], sc[T][8 * g + 3]);
        u32 a2 = cvtpk(sc[T][8 * g + 4], sc[T][8 * g + 5]);
        u32 a3 = cvtpk(sc[T][8 * g + 6], sc[T][8 * g + 7]);
        u32 x0 = (u32)__shfl_xor((int)a0, 32);
        u32 x1 = (u32)__shfl_xor((int)a1, 32);
        u32 x2 = (u32)__shfl_xor((int)a2, 32);
        u32 x3 = (u32)__shfl_xor((int)a3, 32);
        u32 s0 = hi ? x2 : a0;
        u32 s1 = hi ? x3 : a1;
        u32 s2 = hi ? a2 : x0;
        u32 s3 = hi ? a3 : x1;
        u32x4 w = {s0, s1, s2, s3};
        pf[T * 2 + g] = __builtin_bit_cast(bf16x8, w);
      }
    }

    __builtin_amdgcn_s_setprio(1);
#pragma unroll
    for (int ks2 = 0; ks2 < 4; ++ks2) {
#pragma unroll
      for (int dt = 0; dt < 4; ++dt) {
        int row = dt * 32 + l31;
        bf16x8 vf = *(const bf16x8*)(lVc + ((row * 128 + ks2 * 32 + hi * 16) ^ ((row & 7) << 4)));
        o[dt] = __builtin_amdgcn_mfma_f32_32x32x16_bf16(vf, pf[ks2], o[dt], 0, 0, 0);
      }
    }
    __builtin_amdgcn_s_setprio(0);

    if (kt < 31) {
      char* nK = lds + (cur ^ 1) * 32768;
      char* nV = nK + 16384;
#pragma unroll
      for (int i = 0; i < 2; ++i) {
        *(bf16x8*)(nK + ((krow[i] * 256 + kc[i] * 16) ^ ((krow[i] & 15) << 4))) = kreg[i];
        *(bf16x8*)(nV + ((vrow[i] * 128 + vc[i] * 16) ^ ((vrow[i] & 7) << 4))) = vreg[i];
      }
    }
    __syncthreads();
  }

  // epilogue: O^T -> O via per-wave LDS region (8KB each), then coalesced stores
  float inv = 1.0f / lrun;
  char* myreg = lds + wid * 8192;  // [32 q][128 d] bf16, XOR (q&15)<<4 on byte-in-row
#pragma unroll
  for (int dt = 0; dt < 4; ++dt)
#pragma unroll
    for (int t = 0; t < 8; ++t) {
      u32 w = cvtpk(o[dt][2 * t] * inv, o[dt][2 * t + 1] * inv);
      int d0 = dt * 32 + 2 * (t & 1) + 8 * (t >> 1) + 4 * hi;
      *(u32*)(myreg + ((l31 * 256 + d0 * 2) ^ ((l31 & 15) << 4))) = w;
    }
  asm volatile("s_waitcnt lgkmcnt(0)");
  {
    int q = lane >> 1, hf = lane & 1;
    int srow = qt * 256 + wid * 32 + q;
    u16* orow = Ob + ((size_t)(b * S_ + srow)) * HID_ + h * 128 + hf * 64;
#pragma unroll
    for (int i = 0; i < 8; ++i) {
      bf16x8 vv = *(const bf16x8*)(myreg + ((q * 256 + hf * 128 + i * 16) ^ ((q & 15) << 4)));
      *(bf16x8*)(orow + i * 8) = vv;
    }
  }
}

extern "C" void kernel_launch(void* const* d_in, const int* in_sizes, int n_in,
                              void* d_out, int out_size, void* d_ws, size_t ws_size,
                              hipStream_t stream) {
  const float* hs = (const float*)d_in[0];
  const float* cosb = (const float*)d_in[1];
  const float* sinb = (const float*)d_in[2];
  const float* w_qkv = (const float*)d_in[3];
  const float* b_qkv = (const float*)d_in[4];
  const float* w_o = (const float*)d_in[5];
  const float* b_o = (const float*)d_in[6];
  float* out = (float*)d_out;

  char* ws = (char*)d_ws;
  u16* Xb    = (u16*)ws;                          // 16,777,216 B (reused as attn_out)
  u16* Wqkvb = (u16*)(ws + 16777216);             // 12,582,912 B
  u16* Wob   = (u16*)(ws + 29360128);             //  8,388,608 B
  u16* qkvb  = (u16*)(ws + 37748736);             // 25,165,824 B (bf16)
  u16* Qb    = (u16*)(ws + 62914560);             // 16,777,216 B
  u16* Kb    = (u16*)(ws + 79691776);             //  4,194,304 B
  u16* Vt    = (u16*)(ws + 83886080);             //  4,194,304 B  (total 88,080,384 B)
  u16* Ob = Xb;

  hipLaunchKernelGGL(k_cvt3, dim3(2048), dim3(256), 0, stream,
                     hs, Xb, (B_ * S_ * HID_) / 8,
                     w_qkv, Wqkvb, (NQKV_ * HID_) / 8,
                     w_o, Wob, (HID_ * HID_) / 8);
  hipLaunchKernelGGL((k_gemm8p<256, u16>), dim3(NQKV_ / 256, (B_ * S_) / 256), dim3(512), 0, stream,
                     Xb, Wqkvb, b_qkv, qkvb, B_ * S_, NQKV_, HID_);
  hipLaunchKernelGGL(k_rope_split, dim3(B_ * S_), dim3(256), 0, stream, qkvb, cosb, sinb, Qb, Kb, Vt);
  hipLaunchKernelGGL(k_attn, dim3(S_ / 256, B_ * H_), dim3(512), 0, stream, Qb, Kb, Vt, Ob);
  hipLaunchKernelGGL((k_gemm8p<128, float>), dim3(HID_ / 256, (B_ * S_) / 128), dim3(512), 0, stream,
                     Ob, Wob, b_o, out, B_ * S_, HID_, HID_);
}

// Round 19
// 213.986 us; speedup vs baseline: 2.0312x; 1.0164x over previous
//
#include <hip/hip_runtime.h>
#include <hip/hip_bf16.h>
#include <stdint.h>

typedef __bf16 bf16x8 __attribute__((ext_vector_type(8)));
typedef float f32x4 __attribute__((ext_vector_type(4)));
typedef float f32x16 __attribute__((ext_vector_type(16)));
typedef float f32x4v __attribute__((ext_vector_type(4)));
typedef unsigned short u16;
typedef unsigned int u32;
typedef u16 u16x8 __attribute__((ext_vector_type(8)));
typedef u32 u32x2 __attribute__((ext_vector_type(2)));
typedef u32 u32x4 __attribute__((ext_vector_type(4)));

#define B_ 2
#define S_ 2048
#define HID_ 2048
#define H_ 16
#define HK_ 4
#define D_ 128
#define NQKV_ 3072

__device__ __forceinline__ u16 f2bf(float f) {
  u32 u = __builtin_bit_cast(u32, f);
  u32 r = (u + 0x7fffu + ((u >> 16) & 1u)) >> 16;
  return (u16)r;
}
__device__ __forceinline__ float bf2f(u16 v) {
  u32 u = ((u32)v) << 16;
  return __builtin_bit_cast(float, u);
}
__device__ __forceinline__ u32 cvtpk(float lo, float hi) {
  u32 r;
  asm("v_cvt_pk_bf16_f32 %0, %1, %2" : "=v"(r) : "v"(lo), "v"(hi));
  return r;
}
__device__ __forceinline__ void gload_lds16(const void* g, void* l) {
  __builtin_amdgcn_global_load_lds((const __attribute__((address_space(1))) void*)g,
                                   (__attribute__((address_space(3))) void*)l, 16, 0, 0);
}

// ---------------- fused f32 -> bf16 convert for 3 buffers ----------------
__global__ __launch_bounds__(256) void k_cvt3(const float* __restrict__ a, u16* __restrict__ oa, int na,
                                              const float* __restrict__ b, u16* __restrict__ ob, int nb,
                                              const float* __restrict__ c, u16* __restrict__ oc, int nc) {
  int total = na + nb + nc;
  for (int i = blockIdx.x * 256 + threadIdx.x; i < total; i += gridDim.x * 256) {
    const float* src;
    u16* dst;
    int j = i;
    if (j < na) { src = a; dst = oa; }
    else if (j < na + nb) { j -= na; src = b; dst = ob; }
    else { j -= na + nb; src = c; dst = oc; }
    const f32x4v* p = (const f32x4v*)(src + (size_t)j * 8);
    f32x4v x = p[0], y = p[1];
    u16x8 w;
    w[0] = f2bf(x[0]); w[1] = f2bf(x[1]); w[2] = f2bf(x[2]); w[3] = f2bf(x[3]);
    w[4] = f2bf(y[0]); w[5] = f2bf(y[1]); w[6] = f2bf(y[2]); w[7] = f2bf(y[3]);
    *(u16x8*)(dst + (size_t)j * 8) = w;
  }
}

// ---------------- 8-phase deep-pipelined GEMM: C = A[M][K] . B[N][K]^T + bias ----
// T1: XCD-aware bijective block swizzle (nwg % 8 == 0 for all launches here).
template <int ISSUES>
__device__ __forceinline__ void stage_half(const u16* __restrict__ src, int K, char* ldsb, int tid) {
#pragma unroll
  for (int i = 0; i < ISSUES; ++i) {
    int off = i * 8192 + tid * 16;
    int r = off >> 7, cb = off & 127;
    int scb = cb ^ ((r & 7) << 4);
    gload_lds16((const char*)(src + (size_t)r * K) + scb, ldsb + i * 8192 + (tid & ~63) * 16);
  }
}

template <int BM, typename CT>
__global__ __launch_bounds__(512, 1) void k_gemm8p(const u16* __restrict__ A, const u16* __restrict__ Bm,
                                                   const float* __restrict__ bias, CT* __restrict__ C,
                                                   int M, int N, int K) {
  constexpr int HAR = BM / 2;            // rows per A half-tile
  constexpr int AHB = HAR * 128;         // bytes per A half-tile
  constexpr int AISS = AHB / 8192;       // gload issues per A half
  constexpr int MREP = BM / 32;          // 16-row frags per wave
  constexpr int MQ = MREP / 4;           // m-frags per phase
  constexpr int DB = 2 * AHB + 32768;    // dbuf stride
  __shared__ __attribute__((aligned(16))) char lds[2 * DB];
  const int tid = threadIdx.x, lane = tid & 63;
  const int wid = tid >> 6, wm = wid >> 2, wn = wid & 3;
  const int l15 = lane & 15, l4 = lane >> 4;
  // T1 swizzle: each XCD gets a contiguous chunk of tile space
  const int nwg = gridDim.x * gridDim.y;
  const int bid = blockIdx.y * gridDim.x + blockIdx.x;
  const int wgid = (bid & 7) * (nwg >> 3) + (bid >> 3);
  const int bx = wgid % gridDim.x, by = wgid / gridDim.x;
  const int row0 = by * BM, col0 = bx * 256;
  const int NT = K >> 6;

  f32x4 acc[MREP][4] = {};

  auto stageA = [&](int t, int h) {
    stage_half<AISS>(A + (size_t)(row0 + h * HAR) * K + t * 64, K, lds + (t & 1) * DB + h * AHB, tid);
  };
  auto stageB = [&](int t, int h) {
    stage_half<2>(Bm + (size_t)(col0 + h * 128) * K + t * 64, K, lds + (t & 1) * DB + 2 * AHB + h * 16384, tid);
  };

  stageA(0, 0); stageA(0, 1); stageB(0, 0); stageB(0, 1);
  if (NT > 1) { stageB(1, 0); stageB(1, 1); }
  if (NT > 1) asm volatile("s_waitcnt vmcnt(4)" ::: "memory");
  else        asm volatile("s_waitcnt vmcnt(0)" ::: "memory");
  __builtin_amdgcn_s_barrier();

  const char* myA = lds + wm * AHB;
  const char* myB = lds + 2 * AHB + (wn >> 1) * 16384;
  const int rBb = (wn & 1) * 64;

  for (int t = 0; t < NT; ++t) {
    const int d = t & 1;
    const char* Ab = myA + d * DB;
    const char* Bb = myB + d * DB;
    bf16x8 bfr[4][2];
#pragma unroll
    for (int j = 0; j < 4; ++j) {
      if (j == 0) {
#pragma unroll
        for (int n = 0; n < 4; ++n)
#pragma unroll
          for (int ks = 0; ks < 2; ++ks) {
            int r = rBb + n * 16 + l15;
            bfr[n][ks] = *(const bf16x8*)(Bb + r * 128 + ((ks * 64 + l4 * 16) ^ ((r & 7) << 4)));
          }
      }
      bf16x8 afr[MQ][2];
#pragma unroll
      for (int mq = 0; mq < MQ; ++mq)
#pragma unroll
        for (int ks = 0; ks < 2; ++ks) {
          int r = (j * MQ + mq) * 16 + l15;
          afr[mq][ks] = *(const bf16x8*)(Ab + r * 128 + ((ks * 64 + l4 * 16) ^ ((r & 7) << 4)));
        }
      if (j == 0) { if (t + 1 < NT) stageA(t + 1, 0); }
      else if (j == 1) { if (t + 1 < NT) stageA(t + 1, 1); }
      else if (j == 2) { if (t + 2 < NT) stageB(t + 2, 0); }
      else {
        if (t + 2 < NT) { stageB(t + 2, 1); asm volatile("s_waitcnt vmcnt(4)" ::: "memory"); }
        else             asm volatile("s_waitcnt vmcnt(0)" ::: "memory");
      }
      __builtin_amdgcn_s_barrier();
      asm volatile("s_waitcnt lgkmcnt(0)" ::: "memory");
      __builtin_amdgcn_s_setprio(1);
#pragma unroll
      for (int mq = 0; mq < MQ; ++mq)
#pragma unroll
        for (int ks = 0; ks < 2; ++ks)
#pragma unroll
          for (int n = 0; n < 4; ++n)
            acc[j * MQ + mq][n] =
                __builtin_amdgcn_mfma_f32_16x16x32_bf16(afr[mq][ks], bfr[n][ks], acc[j * MQ + mq][n], 0, 0, 0);
      __builtin_amdgcn_s_setprio(0);
      __builtin_amdgcn_s_barrier();
    }
  }

#pragma unroll
  for (int m = 0; m < MREP; ++m) {
    int grow = row0 + wm * HAR + m * 16 + l4 * 4;
#pragma unroll
    for (int n = 0; n < 4; ++n) {
      int gcol = col0 + wn * 64 + n * 16 + l15;
      float bv = bias[gcol];
#pragma unroll
      for (int r2 = 0; r2 < 4; ++r2) {
        float v = acc[m][n][r2] + bv;
        if constexpr (sizeof(CT) == 2) C[(size_t)(grow + r2) * N + gcol] = (CT)f2bf(v);
        else                           C[(size_t)(grow + r2) * N + gcol] = v;
      }
    }
  }
}

// ---------------- RoPE + split + layout (qkv bf16), vectorized bf16x8 ----------------
__global__ __launch_bounds__(256) void k_rope_split(const u16* __restrict__ qkv,
                                                    const float* __restrict__ cosb,
                                                    const float* __restrict__ sinb,
                                                    u16* __restrict__ Qb, u16* __restrict__ Kb,
                                                    u16* __restrict__ Vt) {
  const int bs = blockIdx.x;
  const int b = bs >> 11, s = bs & 2047;
  const size_t base = (size_t)bs * NQKV_;
  const size_t cs = (size_t)bs * D_;
  const int tid = threadIdx.x;
  const float qscale = 0.08838834764831845f;  // 1/sqrt(128)

  if (tid < 160) {
    const bool isq = tid < 128;
    const int idx = isq ? tid : (tid - 128);
    const int hh = idx >> 3, d0 = (idx & 7) * 8;
    const size_t srcb = base + (isq ? 0 : H_ * D_) + hh * D_;
    bf16x8 x1 = *(const bf16x8*)(qkv + srcb + d0);
    bf16x8 x2 = *(const bf16x8*)(qkv + srcb + d0 + 64);
    u16x8 y1, y2;
    const u16x8 u1 = __builtin_bit_cast(u16x8, x1);
    const u16x8 u2 = __builtin_bit_cast(u16x8, x2);
    const float sc = isq ? qscale : 1.0f;
#pragma unroll
    for (int i = 0; i < 8; ++i) {
      float f1 = bf2f(u1[i]), f2 = bf2f(u2[i]);
      float c1 = cosb[cs + d0 + i], s1 = sinb[cs + d0 + i];
      float c2 = cosb[cs + 64 + d0 + i], s2 = sinb[cs + 64 + d0 + i];
      y1[i] = f2bf((f1 * c1 - f2 * s1) * sc);
      y2[i] = f2bf((f2 * c2 + f1 * s2) * sc);
    }
    size_t o;
    if (isq) o = ((size_t)(b * H_ + hh) * S_ + s) * D_ + d0;
    else     o = ((size_t)(b * HK_ + hh) * S_ + s) * D_ + d0;
    u16* dst = isq ? Qb : Kb;
    *(u16x8*)(dst + o) = y1;
    *(u16x8*)(dst + o + 64) = y2;
  } else if (tid < 224) {
    const int idx = tid - 160;
    const int hk = idx >> 4, d0 = (idx & 15) * 8;
    bf16x8 xv = *(const bf16x8*)(qkv + base + (H_ + HK_) * D_ + hk * D_ + d0);
    const u16x8 uv = __builtin_bit_cast(u16x8, xv);
    u16* vb = Vt + (size_t)(b * HK_ + hk) * D_ * S_ + s;
#pragma unroll
    for (int i = 0; i < 8; ++i) vb[(size_t)(d0 + i) * S_] = uv[i];
  }
}

// ---------------- flash attention: 8 waves x 32 q-rows, 32x32 MFMA, swapped QK^T,
//                  in-register softmax (shfl reduces) + T12 permlane PACK
//                  (distinct-input swaps only — same-input swap aliased in R18),
//                  O^T = V^T . P^T, LDS double-buffer, one barrier per kv-tile ----------------
__global__ __launch_bounds__(512, 2) void k_attn(const u16* __restrict__ Qb, const u16* __restrict__ Kb,
                                                 const u16* __restrict__ Vt, u16* __restrict__ Ob) {
  __shared__ __attribute__((aligned(16))) char lds[65536];
  const int qt = blockIdx.x;  // 0..7
  const int bh = blockIdx.y;  // 0..31
  const int b = bh >> 4, h = bh & 15, hk = h >> 2;
  const int tid = threadIdx.x, lane = tid & 63, wid = tid >> 6;
  const int l31 = lane & 31, hi = lane >> 5;

  const int qrow = qt * 256 + wid * 32 + l31;
  const u16* qptr = Qb + ((size_t)(b * H_ + h) * S_ + qrow) * D_;
  bf16x8 qf[8];
#pragma unroll
  for (int ks = 0; ks < 8; ++ks) qf[ks] = *(const bf16x8*)(qptr + ks * 16 + hi * 8);

  const u16* kbase = Kb + (size_t)(b * HK_ + hk) * S_ * D_;
  const u16* vbase = Vt + (size_t)(b * HK_ + hk) * D_ * S_;

  int krow[2], kc[2], vrow[2], vc[2];
#pragma unroll
  for (int i = 0; i < 2; ++i) {
    int s = tid + i * 512;
    krow[i] = s >> 4; kc[i] = s & 15;
    vrow[i] = s >> 3; vc[i] = s & 7;
  }

  f32x16 o[4] = {};
  float mrun = -1e30f, lrun = 0.f;

  bf16x8 kreg[2], vreg[2];
#pragma unroll
  for (int i = 0; i < 2; ++i) {
    kreg[i] = *(const bf16x8*)(kbase + (size_t)krow[i] * D_ + kc[i] * 8);
    vreg[i] = *(const bf16x8*)(vbase + (size_t)vrow[i] * S_ + vc[i] * 8);
  }
#pragma unroll
  for (int i = 0; i < 2; ++i) {
    *(bf16x8*)(lds + ((krow[i] * 256 + kc[i] * 16) ^ ((krow[i] & 15) << 4))) = kreg[i];
    *(bf16x8*)(lds + 16384 + ((vrow[i] * 128 + vc[i] * 16) ^ ((vrow[i] & 7) << 4))) = vreg[i];
  }
  __syncthreads();

  for (int kt = 0; kt < 32; ++kt) {
    const int cur = kt & 1;
    const char* lKc = lds + cur * 32768;
    const char* lVc = lKc + 16384;

    if (kt < 31) {
#pragma unroll
      for (int i = 0; i < 2; ++i) {
        kreg[i] = *(const bf16x8*)(kbase + (size_t)((kt + 1) * 64 + krow[i]) * D_ + kc[i] * 8);
        vreg[i] = *(const bf16x8*)(vbase + (size_t)vrow[i] * S_ + (kt + 1) * 64 + vc[i] * 8);
      }
    }

    f32x16 sc[2] = {};
    __builtin_amdgcn_s_setprio(1);
#pragma unroll
    for (int ks = 0; ks < 8; ++ks) {
#pragma unroll
      for (int T = 0; T < 2; ++T) {
        int row = T * 32 + l31;
        bf16x8 kf = *(const bf16x8*)(lKc + ((row * 256 + ks * 32 + hi * 16) ^ ((row & 15) << 4)));
        sc[T] = __builtin_amdgcn_mfma_f32_32x32x16_bf16(kf, qf[ks], sc[T], 0, 0, 0);
      }
    }
    __builtin_amdgcn_s_setprio(0);

    float pmax = sc[0][0];
#pragma unroll
    for (int r = 1; r < 16; ++r) pmax = fmaxf(pmax, sc[0][r]);
#pragma unroll
    for (int r = 0; r < 16; ++r) pmax = fmaxf(pmax, sc[1][r]);
    pmax = fmaxf(pmax, __shfl_xor(pmax, 32));   // proven-correct cross-half max
    if (__any(pmax > mrun + 8.f)) {   // T13 defer-max
      float mn = fmaxf(mrun, pmax);
      float alpha = __expf(mrun - mn);
      mrun = mn;
      lrun *= alpha;
#pragma unroll
      for (int dt = 0; dt < 4; ++dt)
#pragma unroll
        for (int r = 0; r < 16; ++r) o[dt][r] *= alpha;
    }
    float rs = 0.f;
#pragma unroll
    for (int T = 0; T < 2; ++T)
#pragma unroll
      for (int r = 0; r < 16; ++r) {
        float p = __expf(sc[T][r] - mrun);
        sc[T][r] = p;
        rs += p;
      }
    rs += __shfl_xor(rs, 32);                   // proven-correct cross-half sum
    lrun += rs;

    // T12 pack via permlane32_swap builtin (inputs distinct -> no aliasing hazard).
    // swap(a0,a2): out0={a0.lo,a2.lo}->word0, out1={a0.hi,a2.hi}->word2; (a1,a3)->words1,3.
    bf16x8 pf[4];
#pragma unroll
    for (int T = 0; T < 2; ++T) {
#pragma unroll
      for (int g = 0; g < 2; ++g) {
        u32 a0 = cvtpk(sc[T][8 * g + 0], sc[T][8 * g + 1]);
        u32 a1 = cvtpk(sc[T][8 * g + 2], sc[T][8 * g + 3]);
        u32 a2 = cvtpk(sc[T][8 * g + 4], sc[T][8 * g + 5]);
        u32 a3 = cvtpk(sc[T][8 * g + 6], sc[T][8 * g + 7]);
        u32x2 s02 = __builtin_amdgcn_permlane32_swap(a0, a2, false, false);
        u32x2 s13 = __builtin_amdgcn_permlane32_swap(a1, a3, false, false);
        u32x4 w = {s02[0], s13[0], s02[1], s13[1]};
        pf[T * 2 + g] = __builtin_bit_cast(bf16x8, w);
      }
    }

    __builtin_amdgcn_s_setprio(1);
#pragma unroll
    for (int ks2 = 0; ks2 < 4; ++ks2) {
#pragma unroll
      for (int dt = 0; dt < 4; ++dt) {
        int row = dt * 32 + l31;
        bf16x8 vf = *(const bf16x8*)(lVc + ((row * 128 + ks2 * 32 + hi * 16) ^ ((row & 7) << 4)));
        o[dt] = __builtin_amdgcn_mfma_f32_32x32x16_bf16(vf, pf[ks2], o[dt], 0, 0, 0);
      }
    }
    __builtin_amdgcn_s_setprio(0);

    if (kt < 31) {
      char* nK = lds + (cur ^ 1) * 32768;
      char* nV = nK + 16384;
#pragma unroll
      for (int i = 0; i < 2; ++i) {
        *(bf16x8*)(nK + ((krow[i] * 256 + kc[i] * 16) ^ ((krow[i] & 15) << 4))) = kreg[i];
        *(bf16x8*)(nV + ((vrow[i] * 128 + vc[i] * 16) ^ ((vrow[i] & 7) << 4))) = vreg[i];
      }
    }
    __syncthreads();
  }

  // epilogue: O^T -> O via per-wave LDS region (8KB each), then coalesced stores
  float inv = 1.0f / lrun;
  char* myreg = lds + wid * 8192;  // [32 q][128 d] bf16, XOR (q&15)<<4 on byte-in-row
#pragma unroll
  for (int dt = 0; dt < 4; ++dt)
#pragma unroll
    for (int t = 0; t < 8; ++t) {
      u32 w = cvtpk(o[dt][2 * t] * inv, o[dt][2 * t + 1] * inv);
      int d0 = dt * 32 + 2 * (t & 1) + 8 * (t >> 1) + 4 * hi;
      *(u32*)(myreg + ((l31 * 256 + d0 * 2) ^ ((l31 & 15) << 4))) = w;
    }
  asm volatile("s_waitcnt lgkmcnt(0)");
  {
    int q = lane >> 1, hf = lane & 1;
    int srow = qt * 256 + wid * 32 + q;
    u16* orow = Ob + ((size_t)(b * S_ + srow)) * HID_ + h * 128 + hf * 64;
#pragma unroll
    for (int i = 0; i < 8; ++i) {
      bf16x8 vv = *(const bf16x8*)(myreg + ((q * 256 + hf * 128 + i * 16) ^ ((q & 15) << 4)));
      *(bf16x8*)(orow + i * 8) = vv;
    }
  }
}

extern "C" void kernel_launch(void* const* d_in, const int* in_sizes, int n_in,
                              void* d_out, int out_size, void* d_ws, size_t ws_size,
                              hipStream_t stream) {
  const float* hs = (const float*)d_in[0];
  const float* cosb = (const float*)d_in[1];
  const float* sinb = (const float*)d_in[2];
  const float* w_qkv = (const float*)d_in[3];
  const float* b_qkv = (const float*)d_in[4];
  const float* w_o = (const float*)d_in[5];
  const float* b_o = (const float*)d_in[6];
  float* out = (float*)d_out;

  char* ws = (char*)d_ws;
  u16* Xb    = (u16*)ws;                          // 16,777,216 B (reused as attn_out)
  u16* Wqkvb = (u16*)(ws + 16777216);             // 12,582,912 B
  u16* Wob   = (u16*)(ws + 29360128);             //  8,388,608 B
  u16* qkvb  = (u16*)(ws + 37748736);             // 25,165,824 B (bf16)
  u16* Qb    = (u16*)(ws + 62914560);             // 16,777,216 B
  u16* Kb    = (u16*)(ws + 79691776);             //  4,194,304 B
  u16* Vt    = (u16*)(ws + 83886080);             //  4,194,304 B  (total 88,080,384 B)
  u16* Ob = Xb;

  hipLaunchKernelGGL(k_cvt3, dim3(2048), dim3(256), 0, stream,
                     hs, Xb, (B_ * S_ * HID_) / 8,
                     w_qkv, Wqkvb, (NQKV_ * HID_) / 8,
                     w_o, Wob, (HID_ * HID_) / 8);
  hipLaunchKernelGGL((k_gemm8p<256, u16>), dim3(NQKV_ / 256, (B_ * S_) / 256), dim3(512), 0, stream,
                     Xb, Wqkvb, b_qkv, qkvb, B_ * S_, NQKV_, HID_);
  hipLaunchKernelGGL(k_rope_split, dim3(B_ * S_), dim3(256), 0, stream, qkvb, cosb, sinb, Qb, Kb, Vt);
  hipLaunchKernelGGL(k_attn, dim3(S_ / 256, B_ * H_), dim3(512), 0, stream, Qb, Kb, Vt, Ob);
  hipLaunchKernelGGL((k_gemm8p<128, float>), dim3(HID_ / 256, (B_ * S_) / 128), dim3(512), 0, stream,
                     Ob, Wob, b_o, out, B_ * S_, HID_, HID_);
}

// Round 20
// 213.556 us; speedup vs baseline: 2.0353x; 1.0020x over previous
//
#include <hip/hip_runtime.h>
#include <hip/hip_bf16.h>
#include <stdint.h>

typedef __bf16 bf16x8 __attribute__((ext_vector_type(8)));
typedef float f32x4 __attribute__((ext_vector_type(4)));
typedef float f32x16 __attribute__((ext_vector_type(16)));
typedef float f32x4v __attribute__((ext_vector_type(4)));
typedef unsigned short u16;
typedef unsigned int u32;
typedef u16 u16x8 __attribute__((ext_vector_type(8)));
typedef u32 u32x2 __attribute__((ext_vector_type(2)));
typedef u32 u32x4 __attribute__((ext_vector_type(4)));

#define B_ 2
#define S_ 2048
#define HID_ 2048
#define H_ 16
#define HK_ 4
#define D_ 128
#define NQKV_ 3072

__device__ __forceinline__ u16 f2bf(float f) {
  u32 u = __builtin_bit_cast(u32, f);
  u32 r = (u + 0x7fffu + ((u >> 16) & 1u)) >> 16;
  return (u16)r;
}
__device__ __forceinline__ float bf2f(u16 v) {
  u32 u = ((u32)v) << 16;
  return __builtin_bit_cast(float, u);
}
__device__ __forceinline__ u32 cvtpk(float lo, float hi) {
  u32 r;
  asm("v_cvt_pk_bf16_f32 %0, %1, %2" : "=v"(r) : "v"(lo), "v"(hi));
  return r;
}
__device__ __forceinline__ void gload_lds16(const void* g, void* l) {
  __builtin_amdgcn_global_load_lds((const __attribute__((address_space(1))) void*)g,
                                   (__attribute__((address_space(3))) void*)l, 16, 0, 0);
}
__device__ __forceinline__ u16x8 cvt8(const float* src) {
  const f32x4v* p = (const f32x4v*)src;
  f32x4v x = p[0], y = p[1];
  u16x8 w;
  w[0] = f2bf(x[0]); w[1] = f2bf(x[1]); w[2] = f2bf(x[2]); w[3] = f2bf(x[3]);
  w[4] = f2bf(y[0]); w[5] = f2bf(y[1]); w[6] = f2bf(y[2]); w[7] = f2bf(y[3]);
  return w;
}

// ---------------- fused f32 -> bf16 convert: hs + w_qkv only (w_o moved to rope) --------
__global__ __launch_bounds__(256) void k_cvt2(const float* __restrict__ a, u16* __restrict__ oa, int na,
                                              const float* __restrict__ b, u16* __restrict__ ob, int nb) {
  int total = na + nb;
  for (int i = blockIdx.x * 256 + threadIdx.x; i < total; i += gridDim.x * 256) {
    const float* src;
    u16* dst;
    int j = i;
    if (j < na) { src = a; dst = oa; }
    else { j -= na; src = b; dst = ob; }
    *(u16x8*)(dst + (size_t)j * 8) = cvt8(src + (size_t)j * 8);
  }
}

// ---------------- 8-phase deep-pipelined GEMM: C = A[M][K] . B[N][K]^T + bias ----
// T1: XCD-aware bijective block swizzle (nwg % 8 == 0 for all launches here).
template <int ISSUES>
__device__ __forceinline__ void stage_half(const u16* __restrict__ src, int K, char* ldsb, int tid) {
#pragma unroll
  for (int i = 0; i < ISSUES; ++i) {
    int off = i * 8192 + tid * 16;
    int r = off >> 7, cb = off & 127;
    int scb = cb ^ ((r & 7) << 4);
    gload_lds16((const char*)(src + (size_t)r * K) + scb, ldsb + i * 8192 + (tid & ~63) * 16);
  }
}

template <int BM, typename CT>
__global__ __launch_bounds__(512, 1) void k_gemm8p(const u16* __restrict__ A, const u16* __restrict__ Bm,
                                                   const float* __restrict__ bias, CT* __restrict__ C,
                                                   int M, int N, int K) {
  constexpr int HAR = BM / 2;            // rows per A half-tile
  constexpr int AHB = HAR * 128;         // bytes per A half-tile
  constexpr int AISS = AHB / 8192;       // gload issues per A half
  constexpr int MREP = BM / 32;          // 16-row frags per wave
  constexpr int MQ = MREP / 4;           // m-frags per phase
  constexpr int DB = 2 * AHB + 32768;    // dbuf stride
  __shared__ __attribute__((aligned(16))) char lds[2 * DB];
  const int tid = threadIdx.x, lane = tid & 63;
  const int wid = tid >> 6, wm = wid >> 2, wn = wid & 3;
  const int l15 = lane & 15, l4 = lane >> 4;
  // T1 swizzle: each XCD gets a contiguous chunk of tile space
  const int nwg = gridDim.x * gridDim.y;
  const int bid = blockIdx.y * gridDim.x + blockIdx.x;
  const int wgid = (bid & 7) * (nwg >> 3) + (bid >> 3);
  const int bx = wgid % gridDim.x, by = wgid / gridDim.x;
  const int row0 = by * BM, col0 = bx * 256;
  const int NT = K >> 6;

  f32x4 acc[MREP][4] = {};

  auto stageA = [&](int t, int h) {
    stage_half<AISS>(A + (size_t)(row0 + h * HAR) * K + t * 64, K, lds + (t & 1) * DB + h * AHB, tid);
  };
  auto stageB = [&](int t, int h) {
    stage_half<2>(Bm + (size_t)(col0 + h * 128) * K + t * 64, K, lds + (t & 1) * DB + 2 * AHB + h * 16384, tid);
  };

  stageA(0, 0); stageA(0, 1); stageB(0, 0); stageB(0, 1);
  if (NT > 1) { stageB(1, 0); stageB(1, 1); }
  if (NT > 1) asm volatile("s_waitcnt vmcnt(4)" ::: "memory");
  else        asm volatile("s_waitcnt vmcnt(0)" ::: "memory");
  __builtin_amdgcn_s_barrier();

  const char* myA = lds + wm * AHB;
  const char* myB = lds + 2 * AHB + (wn >> 1) * 16384;
  const int rBb = (wn & 1) * 64;

  for (int t = 0; t < NT; ++t) {
    const int d = t & 1;
    const char* Ab = myA + d * DB;
    const char* Bb = myB + d * DB;
    bf16x8 bfr[4][2];
#pragma unroll
    for (int j = 0; j < 4; ++j) {
      if (j == 0) {
#pragma unroll
        for (int n = 0; n < 4; ++n)
#pragma unroll
          for (int ks = 0; ks < 2; ++ks) {
            int r = rBb + n * 16 + l15;
            bfr[n][ks] = *(const bf16x8*)(Bb + r * 128 + ((ks * 64 + l4 * 16) ^ ((r & 7) << 4)));
          }
      }
      bf16x8 afr[MQ][2];
#pragma unroll
      for (int mq = 0; mq < MQ; ++mq)
#pragma unroll
        for (int ks = 0; ks < 2; ++ks) {
          int r = (j * MQ + mq) * 16 + l15;
          afr[mq][ks] = *(const bf16x8*)(Ab + r * 128 + ((ks * 64 + l4 * 16) ^ ((r & 7) << 4)));
        }
      if (j == 0) { if (t + 1 < NT) stageA(t + 1, 0); }
      else if (j == 1) { if (t + 1 < NT) stageA(t + 1, 1); }
      else if (j == 2) { if (t + 2 < NT) stageB(t + 2, 0); }
      else {
        if (t + 2 < NT) { stageB(t + 2, 1); asm volatile("s_waitcnt vmcnt(4)" ::: "memory"); }
        else             asm volatile("s_waitcnt vmcnt(0)" ::: "memory");
      }
      __builtin_amdgcn_s_barrier();
      asm volatile("s_waitcnt lgkmcnt(0)" ::: "memory");
      __builtin_amdgcn_s_setprio(1);
#pragma unroll
      for (int mq = 0; mq < MQ; ++mq)
#pragma unroll
        for (int ks = 0; ks < 2; ++ks)
#pragma unroll
          for (int n = 0; n < 4; ++n)
            acc[j * MQ + mq][n] =
                __builtin_amdgcn_mfma_f32_16x16x32_bf16(afr[mq][ks], bfr[n][ks], acc[j * MQ + mq][n], 0, 0, 0);
      __builtin_amdgcn_s_setprio(0);
      __builtin_amdgcn_s_barrier();
    }
  }

#pragma unroll
  for (int m = 0; m < MREP; ++m) {
    int grow = row0 + wm * HAR + m * 16 + l4 * 4;
#pragma unroll
    for (int n = 0; n < 4; ++n) {
      int gcol = col0 + wn * 64 + n * 16 + l15;
      float bv = bias[gcol];
#pragma unroll
      for (int r2 = 0; r2 < 4; ++r2) {
        float v = acc[m][n][r2] + bv;
        if constexpr (sizeof(CT) == 2) C[(size_t)(grow + r2) * N + gcol] = (CT)f2bf(v);
        else                           C[(size_t)(grow + r2) * N + gcol] = v;
      }
    }
  }
}

// ---------------- RoPE + split + layout (qkv bf16) + w_o convert in idle threads ----------
__global__ __launch_bounds__(256) void k_rope_split(const u16* __restrict__ qkv,
                                                    const float* __restrict__ cosb,
                                                    const float* __restrict__ sinb,
                                                    u16* __restrict__ Qb, u16* __restrict__ Kb,
                                                    u16* __restrict__ Vt,
                                                    const float* __restrict__ w_o,
                                                    u16* __restrict__ Wob) {
  const int bs = blockIdx.x;
  const int b = bs >> 11, s = bs & 2047;
  const size_t base = (size_t)bs * NQKV_;
  const size_t cs = (size_t)bs * D_;
  const int tid = threadIdx.x;
  const float qscale = 0.08838834764831845f;  // 1/sqrt(128)

  if (tid < 160) {
    const bool isq = tid < 128;
    const int idx = isq ? tid : (tid - 128);
    const int hh = idx >> 3, d0 = (idx & 7) * 8;
    const size_t srcb = base + (isq ? 0 : H_ * D_) + hh * D_;
    bf16x8 x1 = *(const bf16x8*)(qkv + srcb + d0);
    bf16x8 x2 = *(const bf16x8*)(qkv + srcb + d0 + 64);
    u16x8 y1, y2;
    const u16x8 u1 = __builtin_bit_cast(u16x8, x1);
    const u16x8 u2 = __builtin_bit_cast(u16x8, x2);
    const float sc = isq ? qscale : 1.0f;
#pragma unroll
    for (int i = 0; i < 8; ++i) {
      float f1 = bf2f(u1[i]), f2 = bf2f(u2[i]);
      float c1 = cosb[cs + d0 + i], s1 = sinb[cs + d0 + i];
      float c2 = cosb[cs + 64 + d0 + i], s2 = sinb[cs + 64 + d0 + i];
      y1[i] = f2bf((f1 * c1 - f2 * s1) * sc);
      y2[i] = f2bf((f2 * c2 + f1 * s2) * sc);
    }
    size_t o;
    if (isq) o = ((size_t)(b * H_ + hh) * S_ + s) * D_ + d0;
    else     o = ((size_t)(b * HK_ + hh) * S_ + s) * D_ + d0;
    u16* dst = isq ? Qb : Kb;
    *(u16x8*)(dst + o) = y1;
    *(u16x8*)(dst + o + 64) = y2;
  } else if (tid < 224) {
    const int idx = tid - 160;
    const int hk = idx >> 4, d0 = (idx & 15) * 8;
    bf16x8 xv = *(const bf16x8*)(qkv + base + (H_ + HK_) * D_ + hk * D_ + d0);
    const u16x8 uv = __builtin_bit_cast(u16x8, xv);
    u16* vb = Vt + (size_t)(b * HK_ + hk) * D_ * S_ + s;
#pragma unroll
    for (int i = 0; i < 8; ++i) vb[(size_t)(d0 + i) * S_] = uv[i];
  } else {
    // idle tail: convert w_o. 4096 blocks x 32 threads = 131072; HID*HID/8 = 524288 = 4 each.
    const int gid = bs * 32 + (tid - 224);
#pragma unroll
    for (int k = 0; k < 4; ++k) {
      int j = gid + k * 131072;
      *(u16x8*)(Wob + (size_t)j * 8) = cvt8(w_o + (size_t)j * 8);
    }
  }
}

// ---------------- flash attention: 8 waves x 32 q-rows, 32x32 MFMA, swapped QK^T,
//                  in-register softmax (shfl reduces) + T12 permlane pack,
//                  O^T = V^T . P^T, LDS double-buffer, one barrier per kv-tile ----------------
__global__ __launch_bounds__(512, 2) void k_attn(const u16* __restrict__ Qb, const u16* __restrict__ Kb,
                                                 const u16* __restrict__ Vt, u16* __restrict__ Ob) {
  __shared__ __attribute__((aligned(16))) char lds[65536];
  const int qt = blockIdx.x;  // 0..7
  const int bh = blockIdx.y;  // 0..31
  const int b = bh >> 4, h = bh & 15, hk = h >> 2;
  const int tid = threadIdx.x, lane = tid & 63, wid = tid >> 6;
  const int l31 = lane & 31, hi = lane >> 5;

  const int qrow = qt * 256 + wid * 32 + l31;
  const u16* qptr = Qb + ((size_t)(b * H_ + h) * S_ + qrow) * D_;
  bf16x8 qf[8];
#pragma unroll
  for (int ks = 0; ks < 8; ++ks) qf[ks] = *(const bf16x8*)(qptr + ks * 16 + hi * 8);

  const u16* kbase = Kb + (size_t)(b * HK_ + hk) * S_ * D_;
  const u16* vbase = Vt + (size_t)(b * HK_ + hk) * D_ * S_;

  int krow[2], kc[2], vrow[2], vc[2];
#pragma unroll
  for (int i = 0; i < 2; ++i) {
    int s = tid + i * 512;
    krow[i] = s >> 4; kc[i] = s & 15;
    vrow[i] = s >> 3; vc[i] = s & 7;
  }

  f32x16 o[4] = {};
  float mrun = -1e30f, lrun = 0.f;

  bf16x8 kreg[2], vreg[2];
#pragma unroll
  for (int i = 0; i < 2; ++i) {
    kreg[i] = *(const bf16x8*)(kbase + (size_t)krow[i] * D_ + kc[i] * 8);
    vreg[i] = *(const bf16x8*)(vbase + (size_t)vrow[i] * S_ + vc[i] * 8);
  }
#pragma unroll
  for (int i = 0; i < 2; ++i) {
    *(bf16x8*)(lds + ((krow[i] * 256 + kc[i] * 16) ^ ((krow[i] & 15) << 4))) = kreg[i];
    *(bf16x8*)(lds + 16384 + ((vrow[i] * 128 + vc[i] * 16) ^ ((vrow[i] & 7) << 4))) = vreg[i];
  }
  __syncthreads();

  for (int kt = 0; kt < 32; ++kt) {
    const int cur = kt & 1;
    const char* lKc = lds + cur * 32768;
    const char* lVc = lKc + 16384;

    if (kt < 31) {
#pragma unroll
      for (int i = 0; i < 2; ++i) {
        kreg[i] = *(const bf16x8*)(kbase + (size_t)((kt + 1) * 64 + krow[i]) * D_ + kc[i] * 8);
        vreg[i] = *(const bf16x8*)(vbase + (size_t)vrow[i] * S_ + (kt + 1) * 64 + vc[i] * 8);
      }
    }

    f32x16 sc[2] = {};
    __builtin_amdgcn_s_setprio(1);
#pragma unroll
    for (int ks = 0; ks < 8; ++ks) {
#pragma unroll
      for (int T = 0; T < 2; ++T) {
        int row = T * 32 + l31;
        bf16x8 kf = *(const bf16x8*)(lKc + ((row * 256 + ks * 32 + hi * 16) ^ ((row & 15) << 4)));
        sc[T] = __builtin_amdgcn_mfma_f32_32x32x16_bf16(kf, qf[ks], sc[T], 0, 0, 0);
      }
    }
    __builtin_amdgcn_s_setprio(0);

    float pmax = sc[0][0];
#pragma unroll
    for (int r = 1; r < 16; ++r) pmax = fmaxf(pmax, sc[0][r]);
#pragma unroll
    for (int r = 0; r < 16; ++r) pmax = fmaxf(pmax, sc[1][r]);
    pmax = fmaxf(pmax, __shfl_xor(pmax, 32));   // proven-correct cross-half max
    if (__any(pmax > mrun + 8.f)) {   // T13 defer-max
      float mn = fmaxf(mrun, pmax);
      float alpha = __expf(mrun - mn);
      mrun = mn;
      lrun *= alpha;
#pragma unroll
      for (int dt = 0; dt < 4; ++dt)
#pragma unroll
        for (int r = 0; r < 16; ++r) o[dt][r] *= alpha;
    }
    float rs = 0.f;
#pragma unroll
    for (int T = 0; T < 2; ++T)
#pragma unroll
      for (int r = 0; r < 16; ++r) {
        float p = __expf(sc[T][r] - mrun);
        sc[T][r] = p;
        rs += p;
      }
    rs += __shfl_xor(rs, 32);                   // proven-correct cross-half sum
    lrun += rs;

    // T12 pack via permlane32_swap builtin (inputs distinct -> no aliasing hazard).
    bf16x8 pf[4];
#pragma unroll
    for (int T = 0; T < 2; ++T) {
#pragma unroll
      for (int g = 0; g < 2; ++g) {
        u32 a0 = cvtpk(sc[T][8 * g + 0], sc[T][8 * g + 1]);
        u32 a1 = cvtpk(sc[T][8 * g + 2], sc[T][8 * g + 3]);
        u32 a2 = cvtpk(sc[T][8 * g + 4], sc[T][8 * g + 5]);
        u32 a3 = cvtpk(sc[T][8 * g + 6], sc[T][8 * g + 7]);
        u32x2 s02 = __builtin_amdgcn_permlane32_swap(a0, a2, false, false);
        u32x2 s13 = __builtin_amdgcn_permlane32_swap(a1, a3, false, false);
        u32x4 w = {s02[0], s13[0], s02[1], s13[1]};
        pf[T * 2 + g] = __builtin_bit_cast(bf16x8, w);
      }
    }

    __builtin_amdgcn_s_setprio(1);
#pragma unroll
    for (int ks2 = 0; ks2 < 4; ++ks2) {
#pragma unroll
      for (int dt = 0; dt < 4; ++dt) {
        int row = dt * 32 + l31;
        bf16x8 vf = *(const bf16x8*)(lVc + ((row * 128 + ks2 * 32 + hi * 16) ^ ((row & 7) << 4)));
        o[dt] = __builtin_amdgcn_mfma_f32_32x32x16_bf16(vf, pf[ks2], o[dt], 0, 0, 0);
      }
    }
    __builtin_amdgcn_s_setprio(0);

    if (kt < 31) {
      char* nK = lds + (cur ^ 1) * 32768;
      char* nV = nK + 16384;
#pragma unroll
      for (int i = 0; i < 2; ++i) {
        *(bf16x8*)(nK + ((krow[i] * 256 + kc[i] * 16) ^ ((krow[i] & 15) << 4))) = kreg[i];
        *(bf16x8*)(nV + ((vrow[i] * 128 + vc[i] * 16) ^ ((vrow[i] & 7) << 4))) = vreg[i];
      }
    }
    __syncthreads();
  }

  // epilogue: O^T -> O via per-wave LDS region (8KB each), then coalesced stores
  float inv = 1.0f / lrun;
  char* myreg = lds + wid * 8192;  // [32 q][128 d] bf16, XOR (q&15)<<4 on byte-in-row
#pragma unroll
  for (int dt = 0; dt < 4; ++dt)
#pragma unroll
    for (int t = 0; t < 8; ++t) {
      u32 w = cvtpk(o[dt][2 * t] * inv, o[dt][2 * t + 1] * inv);
      int d0 = dt * 32 + 2 * (t & 1) + 8 * (t >> 1) + 4 * hi;
      *(u32*)(myreg + ((l31 * 256 + d0 * 2) ^ ((l31 & 15) << 4))) = w;
    }
  asm volatile("s_waitcnt lgkmcnt(0)");
  {
    int q = lane >> 1, hf = lane & 1;
    int srow = qt * 256 + wid * 32 + q;
    u16* orow = Ob + ((size_t)(b * S_ + srow)) * HID_ + h * 128 + hf * 64;
#pragma unroll
    for (int i = 0; i < 8; ++i) {
      bf16x8 vv = *(const bf16x8*)(myreg + ((q * 256 + hf * 128 + i * 16) ^ ((q & 15) << 4)));
      *(bf16x8*)(orow + i * 8) = vv;
    }
  }
}

extern "C" void kernel_launch(void* const* d_in, const int* in_sizes, int n_in,
                              void* d_out, int out_size, void* d_ws, size_t ws_size,
                              hipStream_t stream) {
  const float* hs = (const float*)d_in[0];
  const float* cosb = (const float*)d_in[1];
  const float* sinb = (const float*)d_in[2];
  const float* w_qkv = (const float*)d_in[3];
  const float* b_qkv = (const float*)d_in[4];
  const float* w_o = (const float*)d_in[5];
  const float* b_o = (const float*)d_in[6];
  float* out = (float*)d_out;

  char* ws = (char*)d_ws;
  u16* Xb    = (u16*)ws;                          // 16,777,216 B (reused as attn_out)
  u16* Wqkvb = (u16*)(ws + 16777216);             // 12,582,912 B
  u16* Wob   = (u16*)(ws + 29360128);             //  8,388,608 B
  u16* qkvb  = (u16*)(ws + 37748736);             // 25,165,824 B (bf16)
  u16* Qb    = (u16*)(ws + 62914560);             // 16,777,216 B
  u16* Kb    = (u16*)(ws + 79691776);             //  4,194,304 B
  u16* Vt    = (u16*)(ws + 83886080);             //  4,194,304 B  (total 88,080,384 B)
  u16* Ob = Xb;

  hipLaunchKernelGGL(k_cvt2, dim3(2048), dim3(256), 0, stream,
                     hs, Xb, (B_ * S_ * HID_) / 8,
                     w_qkv, Wqkvb, (NQKV_ * HID_) / 8);
  hipLaunchKernelGGL((k_gemm8p<256, u16>), dim3(NQKV_ / 256, (B_ * S_) / 256), dim3(512), 0, stream,
                     Xb, Wqkvb, b_qkv, qkvb, B_ * S_, NQKV_, HID_);
  hipLaunchKernelGGL(k_rope_split, dim3(B_ * S_), dim3(256), 0, stream, qkvb, cosb, sinb, Qb, Kb, Vt,
                     w_o, Wob);
  hipLaunchKernelGGL(k_attn, dim3(S_ / 256, B_ * H_), dim3(512), 0, stream, Qb, Kb, Vt, Ob);
  hipLaunchKernelGGL((k_gemm8p<128, float>), dim3(HID_ / 256, (B_ * S_) / 128), dim3(512), 0, stream,
                     Ob, Wob, b_o, out, B_ * S_, HID_, HID_);
}